// Round 5
// baseline (298.349 us; speedup 1.0000x reference)
//
#include <hip/hip_runtime.h>
#include <math.h>

// Problem constants: B=4, S=2048, D=512, H=8, Hd=64
#define SEQ 2048
#define DM 512
#define NH 8
#define HD 64
#define VST 2176   // vT row stride (2048 + 128 pad: spreads L2 channels)

typedef _Float16 f16x8 __attribute__((ext_vector_type(8)));
typedef _Float16 f16x4 __attribute__((ext_vector_type(4)));
typedef __fp16 h16x2 __attribute__((ext_vector_type(2)));   // builtin ABI type
typedef float f32x4 __attribute__((ext_vector_type(4)));
#define MFMAH(A, B, C) __builtin_amdgcn_mfma_f32_16x16x32_f16(A, B, C, 0, 0, 0)

__device__ __forceinline__ void async16(const void* g, void* l) {
    __builtin_amdgcn_global_load_lds((__attribute__((address_space(1))) void*)g,
                                     (__attribute__((address_space(3))) void*)l,
                                     16, 0, 0);
}
#define LGKM0() asm volatile("s_waitcnt lgkmcnt(0)" ::: "memory")
#define WAITVM(n) asm volatile("s_waitcnt vmcnt(" #n ")" ::: "memory")
#define SB0() __builtin_amdgcn_sched_barrier(0)
#define MEMFENCE() asm volatile("" ::: "memory")
// raw barrier (no implicit vmcnt/lgkmcnt drain) fenced against code motion
#define BAR() do { SB0(); __builtin_amdgcn_s_barrier(); SB0(); } while (0)

// scale = 1/sqrt(64) * log2(e), folded into q at the QKV epilogue;
// scores land in the log2 domain -> exp2, no max subtraction needed.
#define QSCALE 0.18033688011112042f

// ---------------------------------------------------------------------------
// Fused prep kernel (range-dispatched by blockIdx.x).
// ---------------------------------------------------------------------------
__global__ __launch_bounds__(256)
void prep_all(const float* __restrict__ x, const float* __restrict__ Wqkv,
              const float* __restrict__ Wo,
              float2* __restrict__ tab,
              _Float16* __restrict__ wqt_h, _Float16* __restrict__ wqt_l,
              _Float16* __restrict__ wot_h, _Float16* __restrict__ wot_l,
              _Float16* __restrict__ xh)
{
    __shared__ float T[64][65];
    const int bid = blockIdx.x;
    const int tid = threadIdx.x;

    if (bid < 256) {
        int idx = bid * 256 + tid;   // 65536
        int s = idx >> 5, p = idx & 31;
        const float c = -0.28782313662425572f;  // -ln(10000)/32
        float f = (float)s * expf(c * (float)p);
        float sn, cs;
        sincosf(f, &sn, &cs);
        tab[idx] = make_float2(cs, sn);
        return;
    }
    if (bid < 512) {
        const float* W;
        _Float16 *hi, *lo;
        int N, bx, by;
        if (bid < 448) {
            int b = bid - 256;                 // 192 blocks: 24 x 8
            bx = b % 24; by = b / 24;
            W = Wqkv; hi = wqt_h; lo = wqt_l; N = 3 * DM;
        } else {
            int b = bid - 448;                 // 64 blocks: 8 x 8
            bx = b % 8; by = b / 8;
            W = Wo; hi = wot_h; lo = wot_l; N = DM;
        }
        const int c0 = bx * 64, k0 = by * 64;
#pragma unroll
        for (int it = 0; it < 4; ++it) {
            int idx = it * 256 + tid;
            int r = idx >> 4, c4 = (idx & 15) << 2;
            *(float4*)&T[r][c4] = *(const float4*)&W[(size_t)(k0 + r) * N + c0 + c4];
        }
        __syncthreads();
#pragma unroll
        for (int it = 0; it < 4; ++it) {
            int idx = it * 256 + tid;
            int c = idx >> 4, k4 = (idx & 15) << 2;
            f16x4 hv, lv;
#pragma unroll
            for (int r = 0; r < 4; ++r) {
                float w = T[k4 + r][c];
                _Float16 h = (_Float16)w;
                hv[r] = h;
                lv[r] = (_Float16)(w - (float)h);
            }
            size_t off = (size_t)(c0 + c) * DM + k0 + k4;
            *(f16x4*)&hi[off] = hv;
            *(f16x4*)&lo[off] = lv;
        }
        return;
    }
    // x -> fp16 single
    size_t i = ((size_t)(bid - 512) * 256 + tid) << 3;
    float4 a0 = *(const float4*)&x[i];
    float4 a1 = *(const float4*)&x[i + 4];
    float fv[8] = {a0.x, a0.y, a0.z, a0.w, a1.x, a1.y, a1.z, a1.w};
    f16x8 hv;
#pragma unroll
    for (int j = 0; j < 8; ++j) hv[j] = (_Float16)fv[j];
    *(f16x8*)&xh[i] = hv;
}

// ---------------------------------------------------------------------------
// Kernel 1: QKV GEMM, 2-term fp16 MFMA (A=x single fp16, W split hi/lo).
// v: fp16 transposed [B,H,64,VST] (row-padded for L2 channel spread).
// ---------------------------------------------------------------------------
__global__ __launch_bounds__(256)
void qkv_mfma(const _Float16* __restrict__ xh,
              const _Float16* __restrict__ wth, const _Float16* __restrict__ wtl,
              const float* __restrict__ bias, const float2* __restrict__ tab,
              _Float16* __restrict__ qo, _Float16* __restrict__ ko,
              _Float16* __restrict__ vo)
{
    __shared__ __align__(16) _Float16 SM[12288];    // 24 KB
    _Float16* Ah = SM;
    _Float16* Bh = SM + 4096;
    _Float16* Bl = SM + 8192;

    const int tid  = threadIdx.x;
    const int lane = tid & 63;
    const int wave = tid >> 6;
    const int quad = lane >> 4;
    const int m    = lane & 15;
    const int wr   = wave >> 1, wc = wave & 1;
    const int row0 = blockIdx.x * 128;
    const int by   = blockIdx.y;            // 0..11
    const int col0 = by * 128;

    const size_t aoff0 = (size_t)(row0 + wave * 16 + m) * DM + (quad << 3);
    const size_t aoff1 = (size_t)(row0 + (wave + 4) * 16 + m) * DM + (quad << 3);
    const size_t boff0 = (size_t)(col0 + wave * 16 + m) * DM + (quad << 3);
    const size_t boff1 = (size_t)(col0 + (wave + 4) * 16 + m) * DM + (quad << 3);
    _Float16* lA0 = &Ah[wave << 9];     _Float16* lA1 = &Ah[(wave + 4) << 9];
    _Float16* lB0 = &Bh[wave << 9];     _Float16* lB1 = &Bh[(wave + 4) << 9];
    _Float16* lBl0 = &Bl[wave << 9];    _Float16* lBl1 = &Bl[(wave + 4) << 9];

    f32x4 acc[4][4];
#pragma unroll
    for (int i = 0; i < 4; ++i)
#pragma unroll
        for (int j = 0; j < 4; ++j) acc[i][j] = (f32x4){0.f, 0.f, 0.f, 0.f};

    for (int k0 = 0; k0 < DM; k0 += 32) {
        async16(xh + aoff0 + k0, lA0);
        async16(xh + aoff1 + k0, lA1);
        async16(wth + boff0 + k0, lB0);
        async16(wth + boff1 + k0, lB1);
        async16(wtl + boff0 + k0, lBl0);
        async16(wtl + boff1 + k0, lBl1);
        __syncthreads();

        f16x8 av[4], bvh[4], bvl[4];
#pragma unroll
        for (int t = 0; t < 4; ++t) {
            int ai  = ((((wr << 2) + t) << 6) + lane) << 3;
            int bi2 = ((((wc << 2) + t) << 6) + lane) << 3;
            av[t]  = *(const f16x8*)&Ah[ai];
            bvh[t] = *(const f16x8*)&Bh[bi2];
            bvl[t] = *(const f16x8*)&Bl[bi2];
        }
#pragma unroll
        for (int rt = 0; rt < 4; ++rt)
#pragma unroll
            for (int ct = 0; ct < 4; ++ct) {
                acc[rt][ct] = MFMAH(av[rt], bvl[ct], acc[rt][ct]);
                acc[rt][ct] = MFMAH(av[rt], bvh[ct], acc[rt][ct]);
            }
        __syncthreads();
    }

    // ---- epilogue ----
    const int sel   = by >> 2;              // 0=q 1=k 2=v
    const int head  = ((by << 1) + wc) & 7;
    const int row0w = row0 + wr * 64;
    const int bidx  = row0w >> 11;
    const int s0    = row0w & (SEQ - 1);
    const int colw  = col0 + wc * 64;

    float bc[4];
#pragma unroll
    for (int ct = 0; ct < 4; ++ct) bc[ct] = bias[colw + (ct << 4) + m];

    if (sel == 2) {
        // v: direct transposed store [B,H,d,VST], f16x4 along s
#pragma unroll
        for (int ct = 0; ct < 4; ++ct) {
            int d = (ct << 4) + m;
#pragma unroll
            for (int rt = 0; rt < 4; ++rt) {
                f32x4 a = acc[rt][ct];
                f16x4 ov;
#pragma unroll
                for (int rg = 0; rg < 4; ++rg) ov[rg] = (_Float16)(a[rg] + bc[ct]);
                size_t off = ((size_t)((bidx * NH + head) * HD + d)) * VST
                           + s0 + (rt << 4) + (quad << 2);
                *(f16x4*)&vo[off] = ov;
            }
        }
    } else {
        // q/k: per-wave LDS transpose + RoPE + fp16 vector stores
        const float sc = (sel == 0) ? QSCALE : 1.0f;
        _Float16* dh = (sel == 0) ? qo : ko;
        float* tb = (float*)SM + wave * 1088;       // 16 x 68 f32
        const int rr = lane >> 2, jj = lane & 3;
#pragma unroll
        for (int rt = 0; rt < 4; ++rt) {
#pragma unroll
            for (int ct = 0; ct < 4; ++ct)
#pragma unroll
                for (int rg = 0; rg < 4; ++rg)
                    tb[((quad << 2) + rg) * 68 + (ct << 4) + m] =
                        acc[rt][ct][rg] + bc[ct];
            LGKM0();
            int s = (row0w + (rt << 4) + rr) & (SEQ - 1);
#pragma unroll
            for (int i = 0; i < 4; ++i) {
                int c = (jj << 2) + (i << 4);
                float4 vv = *(const float4*)&tb[rr * 68 + c];
                float4 t4 = *(const float4*)&tab[(s << 5) + (c >> 1)];
                f16x4 hv;
                hv[0] = (_Float16)((vv.x * t4.x - vv.y * t4.y) * sc);
                hv[1] = (_Float16)((vv.x * t4.y + vv.y * t4.x) * sc);
                hv[2] = (_Float16)((vv.z * t4.z - vv.w * t4.w) * sc);
                hv[3] = (_Float16)((vv.z * t4.w + vv.w * t4.z) * sc);
                size_t off = (((size_t)(bidx * NH + head) * SEQ + s) << 6) + c;
                *(f16x4*)&dh[off] = hv;
            }
        }
    }
}

// ---------------------------------------------------------------------------
// Kernel 2: fp16 MFMA flash attention. LDS-throughput diet:
//   - K staged in LDS (double buffer, counted vmcnt) — 4-wave reuse.
//   - V read DIRECTLY from L2 into registers (8 f16x8/tile/wave), issued at
//     tile-top, consumed after QK+softmax (~400cy cover). No VF LDS buffer:
//     LDS unit load per wave-tile drops 288 -> 168 cyc (the measured limiter).
//   - XCD-bijective swizzle: all 32 q-blocks of a bh land on one XCD
//     (working set 4 bh x 0.5 MB = 2 MB < 4 MB L2) -> V frags are L2 hits.
//   - vmcnt ledger (issue order per tile: V8 then K2):
//     steady top-of-tile outstanding = K2(t); +V8 +K2(t+1) = 12;
//     WAITVM(10) drains K2(t); compiler auto-waits vmcnt(2) for V before PV.
//     Last tile: no stage -> WAITVM(8).
//   - P C->A frag via rotated stride-64 per-wave LDS (R4-verified).
// LDS: 16 KB KH + 8 KB PW = 24 KB.
// ---------------------------------------------------------------------------
__global__ __launch_bounds__(256, 4)
void attn_mfma(const _Float16* __restrict__ qh_, const _Float16* __restrict__ kh_,
               const _Float16* __restrict__ vt, _Float16* __restrict__ oh)
{
    __shared__ __align__(16) _Float16 KH[2][4096];  // 2 x 8 KB double buffer
    __shared__ __align__(16) _Float16 PW[4][1024];  // per wave 16 x 64 (rotated)

    const int tid  = threadIdx.x;
    const int lane = tid & 63;
    const int wave = tid >> 6;
    const int m    = lane & 15;
    const int quad = lane >> 4;

    // XCD-bijective swizzle: linear id l -> xcd = l&7 (round-robin assumption);
    // assign bh == xcd (mod 8) so each bh's 32 q-blocks share one XCD's L2.
    const int l   = blockIdx.x + (blockIdx.y << 5);
    const int idx = l >> 3;
    const int bh  = (l & 7) + ((idx >> 5) << 3);   // 0..31
    const int qt  = idx & 31;                      // 0..31
    const int bi = bh >> 3, h = bh & 7;

    const _Float16* qhp = qh_ + ((size_t)bh * SEQ + qt * 64 + wave * 16) * HD;
    const _Float16* khp = kh_ + (size_t)bh * SEQ * HD;
    const _Float16* vp  = vt  + (size_t)bh * HD * VST;
    const _Float16* vpl = vp + (size_t)m * VST + (quad << 3);

    // Q B-frags (pre-scaled by QSCALE): B[k=d=c*32+quad*8+j][n=q=m]
    f16x8 qf[2];
#pragma unroll
    for (int c = 0; c < 2; ++c)
        qf[c] = *(const f16x8*)&qhp[((size_t)m << 6) + c * 32 + (quad << 3)];

    f32x4 oacc[4];   // [dt]: D[q=quad*4+rg][d=dt*16+m]
#pragma unroll
    for (int dt = 0; dt < 4; ++dt) oacc[dt] = (f32x4){0.f, 0.f, 0.f, 0.f};
    float lrow = 0.f, lrow2 = 0.f;

    // K staging: wave w stages keys w*16+m, both d-halves
    const size_t koff0 = ((size_t)(wave * 16 + m) << 6) + (quad << 3);
    const size_t koff1 = koff0 + 32;

    const h16x2 ones = {(__fp16)1.f, (__fp16)1.f};
    _Float16* pw = PW[wave];
    const int rot = m << 2;          // per-row key rotation (multiple of 4)

    auto tile = [&](int t, int buf) {
        const _Float16* KB = &KH[buf][0];

        // ---- V frags for tile t, direct from L2 into regs ----
        f16x8 vr0[4], vr1[4];
#pragma unroll
        for (int dt = 0; dt < 4; ++dt) {
            vr0[dt] = *(const f16x8*)&vpl[(size_t)dt * (16 * VST) + (t << 6)];
            vr1[dt] = *(const f16x8*)&vpl[(size_t)dt * (16 * VST) + (t << 6) + 32];
        }
        MEMFENCE();   // pin V-load issue before the async16s (vmcnt ledger)

        if (t + 1 < SEQ / 64) {
            _Float16* ks0 = &KH[buf ^ 1][wave << 9];
            _Float16* ks1 = &KH[buf ^ 1][(wave + 4) << 9];
            async16(khp + koff0 + ((size_t)(t + 1) << 12), ks0);
            async16(khp + koff1 + ((size_t)(t + 1) << 12), ks1);
            WAITVM(10);    // drain K2(t); leave V8(t)+K2(t+1) in flight
        } else {
            WAITVM(8);     // drain K2(t); leave V8(t)
        }
        BAR();             // all waves' K(t) parts staged

        // ---- S^T = K·Q^T : [64 keys][16 q] ----
        f32x4 sv[4];
#pragma unroll
        for (int nt = 0; nt < 4; ++nt) {
            f32x4 s = (f32x4){0.f, 0.f, 0.f, 0.f};
#pragma unroll
            for (int c = 0; c < 2; ++c) {
                f16x8 kf = *(const f16x8*)&KB[((c * 4 + nt) * 64 + lane) << 3];
                s = MFMAH(kf, qf[c], s);
            }
            sv[nt] = s;   // [key=nt*16+quad*4+rg][q=m], log2 domain
        }

        // ---- P = exp2(s); cvt_pkrtz pack; fdot2 l-sum; rotated LDS write ----
#pragma unroll
        for (int nt = 0; nt < 4; ++nt) {
            union { unsigned int u[2]; f16x4 v; } pk;
#pragma unroll
            for (int i = 0; i < 2; ++i) {
                h16x2 tt = __builtin_amdgcn_cvt_pkrtz(exp2f(sv[nt][2 * i]),
                                                      exp2f(sv[nt][2 * i + 1]));
                if (i == 0) lrow  = __builtin_amdgcn_fdot2(tt, ones, lrow,  false);
                else        lrow2 = __builtin_amdgcn_fdot2(tt, ones, lrow2, false);
                union { h16x2 hh; unsigned int uu; } cv; cv.hh = tt;
                pk.u[i] = cv.uu;
            }
            int pos = ((nt << 4) + (quad << 2) + rot) & 63;
            *(f16x4*)&pw[(m << 6) + pos] = pk.v;
        }
        LGKM0();
        union { f16x4 h4[2]; f16x8 w; } u0, u1;
        u0.h4[0] = *(const f16x4*)&pw[(m << 6) + (((quad << 3) + rot) & 63)];
        u0.h4[1] = *(const f16x4*)&pw[(m << 6) + (((quad << 3) + 4 + rot) & 63)];
        u1.h4[0] = *(const f16x4*)&pw[(m << 6) + ((32 + (quad << 3) + rot) & 63)];
        u1.h4[1] = *(const f16x4*)&pw[(m << 6) + ((36 + (quad << 3) + rot) & 63)];
        f16x8 pf0 = u0.w;
        f16x8 pf1 = u1.w;

        // ---- O += P·V (V from regs; compiler waits vmcnt for vr*) ----
#pragma unroll
        for (int dt = 0; dt < 4; ++dt) {
            oacc[dt] = MFMAH(pf0, vr0[dt], oacc[dt]);
            oacc[dt] = MFMAH(pf1, vr1[dt], oacc[dt]);
        }
        LGKM0();           // my ds reads of KB/pw retired
        BAR();             // release buf for restage
    };

    // prologue: stage K(0) into buf 0
    async16(khp + koff0, &KH[0][wave << 9]);
    async16(khp + koff1, &KH[0][(wave + 4) << 9]);

#pragma unroll 1
    for (int kt = 0; kt < SEQ / 64; kt += 2) {
        tile(kt, 0);
        tile(kt + 1, 1);
    }

    // ---- epilogue: reduce l across quads, normalize, fp16 store ----
    lrow += lrow2;
    lrow += __shfl_xor(lrow, 16);
    lrow += __shfl_xor(lrow, 32);
    float inv = 1.0f / lrow;
    size_t ob = ((size_t)(bi * SEQ + qt * 64 + wave * 16 + (quad << 2))) * DM
              + h * HD + m;
#pragma unroll
    for (int rg = 0; rg < 4; ++rg) {
        float il = __shfl(inv, (quad << 2) + rg, 16);
#pragma unroll
        for (int dt = 0; dt < 4; ++dt)
            oh[ob + (size_t)rg * DM + dt * 16] = (_Float16)(oacc[dt][rg] * il);
    }
}

// ---------------------------------------------------------------------------
// Kernel 3: out = attn @ Wo + bo, 2-term fp16 MFMA (A single, W hi/lo).
// ---------------------------------------------------------------------------
__global__ __launch_bounds__(256)
void out_mfma(const _Float16* __restrict__ ah,
              const _Float16* __restrict__ wth, const _Float16* __restrict__ wtl,
              const float* __restrict__ bias, float* __restrict__ out)
{
    __shared__ __align__(16) _Float16 SM[12288];
    _Float16* Ah = SM;
    _Float16* Bh = SM + 4096;
    _Float16* Bl = SM + 8192;

    const int tid  = threadIdx.x;
    const int lane = tid & 63;
    const int wave = tid >> 6;
    const int quad = lane >> 4;
    const int m    = lane & 15;
    const int wr   = wave >> 1, wc = wave & 1;
    const int row0 = blockIdx.x * 128;
    const int col0 = blockIdx.y * 128;

    const size_t aoff0 = (size_t)(row0 + wave * 16 + m) * DM + (quad << 3);
    const size_t aoff1 = (size_t)(row0 + (wave + 4) * 16 + m) * DM + (quad << 3);
    const size_t boff0 = (size_t)(col0 + wave * 16 + m) * DM + (quad << 3);
    const size_t boff1 = (size_t)(col0 + (wave + 4) * 16 + m) * DM + (quad << 3);
    _Float16* lA0 = &Ah[wave << 9];     _Float16* lA1 = &Ah[(wave + 4) << 9];
    _Float16* lB0 = &Bh[wave << 9];     _Float16* lB1 = &Bh[(wave + 4) << 9];
    _Float16* lBl0 = &Bl[wave << 9];    _Float16* lBl1 = &Bl[(wave + 4) << 9];

    f32x4 acc[4][4];
#pragma unroll
    for (int i = 0; i < 4; ++i)
#pragma unroll
        for (int j = 0; j < 4; ++j) acc[i][j] = (f32x4){0.f, 0.f, 0.f, 0.f};

    for (int k0 = 0; k0 < DM; k0 += 32) {
        async16(ah + aoff0 + k0, lA0);
        async16(ah + aoff1 + k0, lA1);
        async16(wth + boff0 + k0, lB0);
        async16(wth + boff1 + k0, lB1);
        async16(wtl + boff0 + k0, lBl0);
        async16(wtl + boff1 + k0, lBl1);
        __syncthreads();

        f16x8 av[4], bvh[4], bvl[4];
#pragma unroll
        for (int t = 0; t < 4; ++t) {
            int ai  = ((((wr << 2) + t) << 6) + lane) << 3;
            int bi2 = ((((wc << 2) + t) << 6) + lane) << 3;
            av[t]  = *(const f16x8*)&Ah[ai];
            bvh[t] = *(const f16x8*)&Bh[bi2];
            bvl[t] = *(const f16x8*)&Bl[bi2];
        }
#pragma unroll
        for (int rt = 0; rt < 4; ++rt)
#pragma unroll
            for (int ct = 0; ct < 4; ++ct) {
                acc[rt][ct] = MFMAH(av[rt], bvl[ct], acc[rt][ct]);
                acc[rt][ct] = MFMAH(av[rt], bvh[ct], acc[rt][ct]);
            }
        __syncthreads();
    }

    // epilogue: LDS transpose -> coalesced float4 stores
    const int row0w = row0 + wr * 64;
    const int colw  = col0 + wc * 64;
    float bc[4];
#pragma unroll
    for (int ct = 0; ct < 4; ++ct) bc[ct] = bias[colw + (ct << 4) + m];

    float* tb = (float*)SM + wave * 1088;
    const int rr = lane >> 2, jj = lane & 3;
#pragma unroll
    for (int rt = 0; rt < 4; ++rt) {
#pragma unroll
        for (int ct = 0; ct < 4; ++ct)
#pragma unroll
            for (int rg = 0; rg < 4; ++rg)
                tb[((quad << 2) + rg) * 68 + (ct << 4) + m] =
                    acc[rt][ct][rg] + bc[ct];
        LGKM0();
        int n = row0w + (rt << 4) + rr;
#pragma unroll
        for (int i = 0; i < 4; ++i) {
            int c = (jj << 2) + (i << 4);
            *(float4*)&out[(size_t)n * DM + colw + c] =
                *(const float4*)&tb[rr * 68 + c];
        }
    }
}

// ---------------------------------------------------------------------------
extern "C" void kernel_launch(void* const* d_in, const int* in_sizes, int n_in,
                              void* d_out, int out_size, void* d_ws, size_t ws_size,
                              hipStream_t stream)
{
    const float* x    = (const float*)d_in[0];
    const float* Wqkv = (const float*)d_in[1];
    const float* bqkv = (const float*)d_in[2];
    const float* Wo   = (const float*)d_in[3];
    const float* bo   = (const float*)d_in[4];
    float* out = (float*)d_out;

    char* ws = (char*)d_ws;
    const size_t MB = 1024 * 1024;
    _Float16* qh    = (_Float16*)(ws);                       // 8 MB [B,H,S,64]
    _Float16* oh    = (_Float16*)(ws + 8 * MB);              // 8 MB [B,S,512]
    _Float16* kh    = (_Float16*)(ws + 16 * MB);             // 8 MB [B,H,S,64]
    _Float16* vT    = (_Float16*)(ws + 24 * MB);             // 8.5 MB [B,H,64,VST]
    _Float16* xh    = (_Float16*)(ws + 33 * MB);             // 8 MB [8192][512]
    _Float16* wqt_h = (_Float16*)(ws + 41 * MB);             // 1.5 MB
    _Float16* wqt_l = (_Float16*)(ws + 41 * MB + 1536 * 1024);
    _Float16* wot_h = (_Float16*)(ws + 44 * MB);             // 0.5 MB
    _Float16* wot_l = (_Float16*)(ws + 44 * MB + 512 * 1024);
    float2*   rtab  = (float2*)(ws + 45 * MB);               // 0.5 MB

    prep_all<<<2560, 256, 0, stream>>>(x, Wqkv, Wo, rtab, wqt_h, wqt_l,
                                       wot_h, wot_l, xh);
    qkv_mfma<<<dim3(64, 12), 256, 0, stream>>>(xh, wqt_h, wqt_l, bqkv, rtab,
                                               qh, kh, vT);
    attn_mfma<<<dim3(32, 32), 256, 0, stream>>>(qh, kh, vT, oh);
    out_mfma<<<dim3(64, 4), 256, 0, stream>>>(oh, wot_h, wot_l, bo, out);
}

// Round 6
// 216.348 us; speedup vs baseline: 1.3790x; 1.3790x over previous
//
#include <hip/hip_runtime.h>
#include <math.h>

// Problem constants: B=4, S=2048, D=512, H=8, Hd=64
#define SEQ 2048
#define DM 512
#define NH 8
#define HD 64

typedef _Float16 f16x8 __attribute__((ext_vector_type(8)));
typedef _Float16 f16x4 __attribute__((ext_vector_type(4)));
typedef __fp16 h16x2 __attribute__((ext_vector_type(2)));   // builtin ABI type
typedef float f32x4 __attribute__((ext_vector_type(4)));
#define MFMAH(A, B, C) __builtin_amdgcn_mfma_f32_16x16x32_f16(A, B, C, 0, 0, 0)

__device__ __forceinline__ void async16(const void* g, void* l) {
    __builtin_amdgcn_global_load_lds((__attribute__((address_space(1))) void*)g,
                                     (__attribute__((address_space(3))) void*)l,
                                     16, 0, 0);
}
#define LGKM0() asm volatile("s_waitcnt lgkmcnt(0)" ::: "memory")
#define WAITVM(n) asm volatile("s_waitcnt vmcnt(" #n ")" ::: "memory")
#define SB0() __builtin_amdgcn_sched_barrier(0)
// raw barrier (no implicit vmcnt/lgkmcnt drain) fenced against code motion
#define BAR() do { SB0(); __builtin_amdgcn_s_barrier(); SB0(); } while (0)

// native exp2 (scores bounded |s|<=~9: no edge cases, 1-ulp HW accuracy fine)
#if __has_builtin(__builtin_amdgcn_exp2f)
#define EXP2(x) __builtin_amdgcn_exp2f(x)
#else
#define EXP2(x) exp2f(x)
#endif

// scale = 1/sqrt(64) * log2(e), folded into q at the QKV epilogue;
// scores land in the log2 domain -> exp2, no max subtraction needed.
#define QSCALE 0.18033688011112042f

// ---------------------------------------------------------------------------
// Fused prep kernel (range-dispatched by blockIdx.x).
// ---------------------------------------------------------------------------
__global__ __launch_bounds__(256)
void prep_all(const float* __restrict__ x, const float* __restrict__ Wqkv,
              const float* __restrict__ Wo,
              float2* __restrict__ tab,
              _Float16* __restrict__ wqt_h, _Float16* __restrict__ wqt_l,
              _Float16* __restrict__ wot_h, _Float16* __restrict__ wot_l,
              _Float16* __restrict__ xh)
{
    __shared__ float T[64][65];
    const int bid = blockIdx.x;
    const int tid = threadIdx.x;

    if (bid < 256) {
        int idx = bid * 256 + tid;   // 65536
        int s = idx >> 5, p = idx & 31;
        const float c = -0.28782313662425572f;  // -ln(10000)/32
        float f = (float)s * expf(c * (float)p);
        float sn, cs;
        sincosf(f, &sn, &cs);
        tab[idx] = make_float2(cs, sn);
        return;
    }
    if (bid < 512) {
        const float* W;
        _Float16 *hi, *lo;
        int N, bx, by;
        if (bid < 448) {
            int b = bid - 256;                 // 192 blocks: 24 x 8
            bx = b % 24; by = b / 24;
            W = Wqkv; hi = wqt_h; lo = wqt_l; N = 3 * DM;
        } else {
            int b = bid - 448;                 // 64 blocks: 8 x 8
            bx = b % 8; by = b / 8;
            W = Wo; hi = wot_h; lo = wot_l; N = DM;
        }
        const int c0 = bx * 64, k0 = by * 64;
#pragma unroll
        for (int it = 0; it < 4; ++it) {
            int idx = it * 256 + tid;
            int r = idx >> 4, c4 = (idx & 15) << 2;
            *(float4*)&T[r][c4] = *(const float4*)&W[(size_t)(k0 + r) * N + c0 + c4];
        }
        __syncthreads();
#pragma unroll
        for (int it = 0; it < 4; ++it) {
            int idx = it * 256 + tid;
            int c = idx >> 4, k4 = (idx & 15) << 2;
            f16x4 hv, lv;
#pragma unroll
            for (int r = 0; r < 4; ++r) {
                float w = T[k4 + r][c];
                _Float16 h = (_Float16)w;
                hv[r] = h;
                lv[r] = (_Float16)(w - (float)h);
            }
            size_t off = (size_t)(c0 + c) * DM + k0 + k4;
            *(f16x4*)&hi[off] = hv;
            *(f16x4*)&lo[off] = lv;
        }
        return;
    }
    // x -> fp16 single
    size_t i = ((size_t)(bid - 512) * 256 + tid) << 3;
    float4 a0 = *(const float4*)&x[i];
    float4 a1 = *(const float4*)&x[i + 4];
    float fv[8] = {a0.x, a0.y, a0.z, a0.w, a1.x, a1.y, a1.z, a1.w};
    f16x8 hv;
#pragma unroll
    for (int j = 0; j < 8; ++j) hv[j] = (_Float16)fv[j];
    *(f16x8*)&xh[i] = hv;
}

// ---------------------------------------------------------------------------
// Kernel 1: QKV GEMM, 2-term fp16 MFMA (A=x single fp16, W split hi/lo).
// 128x128 tile, 4 waves. Epilogue: LDS transpose -> bias + RoPE.
// q: PRE-SCALED (QSCALE) fp16 [B,H,S,64]; k: fp16 [B,H,S,64];
// v: fp16 transposed [B,H,64,S].
// ---------------------------------------------------------------------------
__global__ __launch_bounds__(256)
void qkv_mfma(const _Float16* __restrict__ xh,
              const _Float16* __restrict__ wth, const _Float16* __restrict__ wtl,
              const float* __restrict__ bias, const float2* __restrict__ tab,
              _Float16* __restrict__ qo, _Float16* __restrict__ ko,
              _Float16* __restrict__ vo)
{
    __shared__ __align__(16) _Float16 SM[12288];    // 24 KB
    _Float16* Ah = SM;
    _Float16* Bh = SM + 4096;
    _Float16* Bl = SM + 8192;

    const int tid  = threadIdx.x;
    const int lane = tid & 63;
    const int wave = tid >> 6;
    const int quad = lane >> 4;
    const int m    = lane & 15;
    const int wr   = wave >> 1, wc = wave & 1;
    const int row0 = blockIdx.x * 128;
    const int by   = blockIdx.y;            // 0..11
    const int col0 = by * 128;

    const size_t aoff0 = (size_t)(row0 + wave * 16 + m) * DM + (quad << 3);
    const size_t aoff1 = (size_t)(row0 + (wave + 4) * 16 + m) * DM + (quad << 3);
    const size_t boff0 = (size_t)(col0 + wave * 16 + m) * DM + (quad << 3);
    const size_t boff1 = (size_t)(col0 + (wave + 4) * 16 + m) * DM + (quad << 3);
    _Float16* lA0 = &Ah[wave << 9];     _Float16* lA1 = &Ah[(wave + 4) << 9];
    _Float16* lB0 = &Bh[wave << 9];     _Float16* lB1 = &Bh[(wave + 4) << 9];
    _Float16* lBl0 = &Bl[wave << 9];    _Float16* lBl1 = &Bl[(wave + 4) << 9];

    f32x4 acc[4][4];
#pragma unroll
    for (int i = 0; i < 4; ++i)
#pragma unroll
        for (int j = 0; j < 4; ++j) acc[i][j] = (f32x4){0.f, 0.f, 0.f, 0.f};

    for (int k0 = 0; k0 < DM; k0 += 32) {
        async16(xh + aoff0 + k0, lA0);
        async16(xh + aoff1 + k0, lA1);
        async16(wth + boff0 + k0, lB0);
        async16(wth + boff1 + k0, lB1);
        async16(wtl + boff0 + k0, lBl0);
        async16(wtl + boff1 + k0, lBl1);
        __syncthreads();

        f16x8 av[4], bvh[4], bvl[4];
#pragma unroll
        for (int t = 0; t < 4; ++t) {
            int ai  = ((((wr << 2) + t) << 6) + lane) << 3;
            int bi2 = ((((wc << 2) + t) << 6) + lane) << 3;
            av[t]  = *(const f16x8*)&Ah[ai];
            bvh[t] = *(const f16x8*)&Bh[bi2];
            bvl[t] = *(const f16x8*)&Bl[bi2];
        }
#pragma unroll
        for (int rt = 0; rt < 4; ++rt)
#pragma unroll
            for (int ct = 0; ct < 4; ++ct) {
                acc[rt][ct] = MFMAH(av[rt], bvl[ct], acc[rt][ct]);
                acc[rt][ct] = MFMAH(av[rt], bvh[ct], acc[rt][ct]);
            }
        __syncthreads();
    }

    // ---- epilogue ----
    const int sel   = by >> 2;              // 0=q 1=k 2=v
    const int head  = ((by << 1) + wc) & 7;
    const int row0w = row0 + wr * 64;
    const int bidx  = row0w >> 11;
    const int s0    = row0w & (SEQ - 1);
    const int colw  = col0 + wc * 64;

    float bc[4];
#pragma unroll
    for (int ct = 0; ct < 4; ++ct) bc[ct] = bias[colw + (ct << 4) + m];

    if (sel == 2) {
        // v: direct transposed store [B,H,d,s], f16x4 along s
#pragma unroll
        for (int ct = 0; ct < 4; ++ct) {
            int d = (ct << 4) + m;
#pragma unroll
            for (int rt = 0; rt < 4; ++rt) {
                f32x4 a = acc[rt][ct];
                f16x4 ov;
#pragma unroll
                for (int rg = 0; rg < 4; ++rg) ov[rg] = (_Float16)(a[rg] + bc[ct]);
                size_t off = ((size_t)((bidx * NH + head) * HD + d)) * SEQ
                           + s0 + (rt << 4) + (quad << 2);
                *(f16x4*)&vo[off] = ov;
            }
        }
    } else {
        // q/k: per-wave LDS transpose + RoPE + fp16 vector stores
        const float sc = (sel == 0) ? QSCALE : 1.0f;
        _Float16* dh = (sel == 0) ? qo : ko;
        float* tb = (float*)SM + wave * 1088;       // 16 x 68 f32
        const int rr = lane >> 2, jj = lane & 3;
#pragma unroll
        for (int rt = 0; rt < 4; ++rt) {
#pragma unroll
            for (int ct = 0; ct < 4; ++ct)
#pragma unroll
                for (int rg = 0; rg < 4; ++rg)
                    tb[((quad << 2) + rg) * 68 + (ct << 4) + m] =
                        acc[rt][ct][rg] + bc[ct];
            LGKM0();
            int s = (row0w + (rt << 4) + rr) & (SEQ - 1);
#pragma unroll
            for (int i = 0; i < 4; ++i) {
                int c = (jj << 2) + (i << 4);
                float4 vv = *(const float4*)&tb[rr * 68 + c];
                float4 t4 = *(const float4*)&tab[(s << 5) + (c >> 1)];
                f16x4 hv;
                hv[0] = (_Float16)((vv.x * t4.x - vv.y * t4.y) * sc);
                hv[1] = (_Float16)((vv.x * t4.y + vv.y * t4.x) * sc);
                hv[2] = (_Float16)((vv.z * t4.z - vv.w * t4.w) * sc);
                hv[3] = (_Float16)((vv.z * t4.w + vv.w * t4.z) * sc);
                size_t off = (((size_t)(bidx * NH + head) * SEQ + s) << 6) + c;
                *(f16x4*)&dh[off] = hv;
            }
        }
    }
}

// ---------------------------------------------------------------------------
// Kernel 2: fp16 MFMA flash attention, 64 q/block, grid 1024 blocks.
// R6 structure (validated pieces only):
//   - XCD swizzle (R5-validated mapping): same-bh blocks colocate per XCD;
//     K/V become L2-resident (R5: FETCH 69.7 -> 12.3 MB).
//   - KVBLK=128: single-buffered 2-tile K/V staging per barrier pair.
//     Drain events halve (32 -> 16); cross-block TLP (4 blocks/CU) covers
//     the drain. LDS = 16K (K) + 16K (V) + 8K (PW) = 40960 B exact.
//   - V read to regs right after QK (overlaps softmax; PV needs no LDS).
//   - Native exp2 builtin (no OCML guard code).
//   - P C->A frag via rotated stride-64 per-wave LDS (R4-validated).
//   - l-sum via fdot2 on the same rounded halves used for PV.
// ---------------------------------------------------------------------------
__global__ __launch_bounds__(256, 4)
void attn_mfma(const _Float16* __restrict__ qh_, const _Float16* __restrict__ kh_,
               const _Float16* __restrict__ vt, _Float16* __restrict__ oh)
{
    __shared__ __align__(16) _Float16 KH[8192];     // 2 tiles x 8 KB
    __shared__ __align__(16) _Float16 VF[8192];     // 2 tiles x 8 KB
    __shared__ __align__(16) _Float16 PW[4][1024];  // per wave 16 x 64 (rotated)

    const int tid  = threadIdx.x;
    const int lane = tid & 63;
    const int wave = tid >> 6;
    const int m    = lane & 15;
    const int quad = lane >> 4;

    // XCD-bijective swizzle (R5-validated): all 32 q-blocks of a bh on one XCD.
    const int l   = blockIdx.x + (blockIdx.y << 5);
    const int idx = l >> 3;
    const int bh  = (l & 7) + ((idx >> 5) << 3);   // 0..31
    const int qt  = idx & 31;                      // 0..31
    const int bi = bh >> 3, h = bh & 7;

    const _Float16* qhp = qh_ + ((size_t)bh * SEQ + qt * 64 + wave * 16) * HD;
    const _Float16* khp = kh_ + (size_t)bh * SEQ * HD;
    const _Float16* vp  = vt  + (size_t)bh * HD * SEQ;

    // Q B-frags (pre-scaled by QSCALE): B[k=d=c*32+quad*8+j][n=q=m]
    f16x8 qf[2];
#pragma unroll
    for (int c = 0; c < 2; ++c)
        qf[c] = *(const f16x8*)&qhp[((size_t)m << 6) + c * 32 + (quad << 3)];

    f32x4 oacc[4];   // [dt]: D[q=quad*4+rg][d=dt*16+m]
#pragma unroll
    for (int dt = 0; dt < 4; ++dt) oacc[dt] = (f32x4){0.f, 0.f, 0.f, 0.f};
    float lrow = 0.f, lrow2 = 0.f;

    // staging offsets: wave w stages K keys w*16+m and V rows d=w*16+m
    const size_t koff0 = ((size_t)(wave * 16 + m) << 6) + (quad << 3);
    const size_t koff1 = koff0 + 32;
    const size_t voff0 = ((size_t)(wave * 16 + m) << 11) + (quad << 3);
    const size_t voff1 = voff0 + 32;

    const h16x2 ones = {(__fp16)1.f, (__fp16)1.f};
    _Float16* pw = PW[wave];
    const int rot = m << 2;          // per-row key rotation (multiple of 4)

    auto tile = [&](const _Float16* KB, const _Float16* VB) {
        // ---- S^T = K·Q^T : [64 keys][16 q] ----
        f32x4 sv[4];
#pragma unroll
        for (int nt = 0; nt < 4; ++nt) {
            f32x4 s = (f32x4){0.f, 0.f, 0.f, 0.f};
#pragma unroll
            for (int c = 0; c < 2; ++c) {
                f16x8 kf = *(const f16x8*)&KB[((c * 4 + nt) * 64 + lane) << 3];
                s = MFMAH(kf, qf[c], s);
            }
            sv[nt] = s;   // [key=nt*16+quad*4+rg][q=m], log2 domain
        }

        // ---- V to regs now: ds latency overlaps the softmax below ----
        f16x8 vr0[4], vr1[4];
#pragma unroll
        for (int dt = 0; dt < 4; ++dt) {
            vr0[dt] = *(const f16x8*)&VB[((0 * 4 + dt) * 64 + lane) << 3];
            vr1[dt] = *(const f16x8*)&VB[((1 * 4 + dt) * 64 + lane) << 3];
        }

        // ---- P = exp2(s); cvt_pkrtz pack; fdot2 l-sum; rotated LDS write ----
#pragma unroll
        for (int nt = 0; nt < 4; ++nt) {
            union { unsigned int u[2]; f16x4 v; } pk;
#pragma unroll
            for (int i = 0; i < 2; ++i) {
                h16x2 tt = __builtin_amdgcn_cvt_pkrtz(EXP2(sv[nt][2 * i]),
                                                      EXP2(sv[nt][2 * i + 1]));
                if (i == 0) lrow  = __builtin_amdgcn_fdot2(tt, ones, lrow,  false);
                else        lrow2 = __builtin_amdgcn_fdot2(tt, ones, lrow2, false);
                union { h16x2 hh; unsigned int uu; } cv; cv.hh = tt;
                pk.u[i] = cv.uu;
            }
            int pos = ((nt << 4) + (quad << 2) + rot) & 63;
            *(f16x4*)&pw[(m << 6) + pos] = pk.v;
        }
        LGKM0();
        union { f16x4 h4[2]; f16x8 w; } u0, u1;
        u0.h4[0] = *(const f16x4*)&pw[(m << 6) + (((quad << 3) + rot) & 63)];
        u0.h4[1] = *(const f16x4*)&pw[(m << 6) + (((quad << 3) + 4 + rot) & 63)];
        u1.h4[0] = *(const f16x4*)&pw[(m << 6) + ((32 + (quad << 3) + rot) & 63)];
        u1.h4[1] = *(const f16x4*)&pw[(m << 6) + ((36 + (quad << 3) + rot) & 63)];
        f16x8 pf0 = u0.w;
        f16x8 pf1 = u1.w;

        // ---- O += P·V (V already in regs) ----
#pragma unroll
        for (int dt = 0; dt < 4; ++dt) {
            oacc[dt] = MFMAH(pf0, vr0[dt], oacc[dt]);
            oacc[dt] = MFMAH(pf1, vr1[dt], oacc[dt]);
        }
    };

    // ---- main loop: 16 super-tiles of 128 keys, single-buffered ----
#pragma unroll 1
    for (int st = 0; st < SEQ / 128; ++st) {
        const size_t t0 = (size_t)st * 2;
        BAR();                       // all reads of previous super-tile done
        async16(khp + koff0 + (t0 << 12), &KH[wave << 9]);
        async16(khp + koff1 + (t0 << 12), &KH[(wave + 4) << 9]);
        async16(khp + koff0 + ((t0 + 1) << 12), &KH[4096 + (wave << 9)]);
        async16(khp + koff1 + ((t0 + 1) << 12), &KH[4096 + ((wave + 4) << 9)]);
        async16(vp + voff0 + (t0 << 6), &VF[wave << 9]);
        async16(vp + voff1 + (t0 << 6), &VF[(wave + 4) << 9]);
        async16(vp + voff0 + ((t0 + 1) << 6), &VF[4096 + (wave << 9)]);
        async16(vp + voff1 + ((t0 + 1) << 6), &VF[4096 + ((wave + 4) << 9)]);
        WAITVM(0);                   // my stages landed
        BAR();                       // everyone's stages landed
        tile(&KH[0], &VF[0]);
        tile(&KH[4096], &VF[4096]);
    }

    // ---- epilogue: reduce l across quads, normalize, fp16 store ----
    lrow += lrow2;
    lrow += __shfl_xor(lrow, 16);
    lrow += __shfl_xor(lrow, 32);
    float inv = 1.0f / lrow;
    size_t ob = ((size_t)(bi * SEQ + qt * 64 + wave * 16 + (quad << 2))) * DM
              + h * HD + m;
#pragma unroll
    for (int rg = 0; rg < 4; ++rg) {
        float il = __shfl(inv, (quad << 2) + rg, 16);
#pragma unroll
        for (int dt = 0; dt < 4; ++dt)
            oh[ob + (size_t)rg * DM + dt * 16] = (_Float16)(oacc[dt][rg] * il);
    }
}

// ---------------------------------------------------------------------------
// Kernel 3: out = attn @ Wo + bo, 2-term fp16 MFMA (A single, W hi/lo).
// ---------------------------------------------------------------------------
__global__ __launch_bounds__(256)
void out_mfma(const _Float16* __restrict__ ah,
              const _Float16* __restrict__ wth, const _Float16* __restrict__ wtl,
              const float* __restrict__ bias, float* __restrict__ out)
{
    __shared__ __align__(16) _Float16 SM[12288];
    _Float16* Ah = SM;
    _Float16* Bh = SM + 4096;
    _Float16* Bl = SM + 8192;

    const int tid  = threadIdx.x;
    const int lane = tid & 63;
    const int wave = tid >> 6;
    const int quad = lane >> 4;
    const int m    = lane & 15;
    const int wr   = wave >> 1, wc = wave & 1;
    const int row0 = blockIdx.x * 128;
    const int col0 = blockIdx.y * 128;

    const size_t aoff0 = (size_t)(row0 + wave * 16 + m) * DM + (quad << 3);
    const size_t aoff1 = (size_t)(row0 + (wave + 4) * 16 + m) * DM + (quad << 3);
    const size_t boff0 = (size_t)(col0 + wave * 16 + m) * DM + (quad << 3);
    const size_t boff1 = (size_t)(col0 + (wave + 4) * 16 + m) * DM + (quad << 3);
    _Float16* lA0 = &Ah[wave << 9];     _Float16* lA1 = &Ah[(wave + 4) << 9];
    _Float16* lB0 = &Bh[wave << 9];     _Float16* lB1 = &Bh[(wave + 4) << 9];
    _Float16* lBl0 = &Bl[wave << 9];    _Float16* lBl1 = &Bl[(wave + 4) << 9];

    f32x4 acc[4][4];
#pragma unroll
    for (int i = 0; i < 4; ++i)
#pragma unroll
        for (int j = 0; j < 4; ++j) acc[i][j] = (f32x4){0.f, 0.f, 0.f, 0.f};

    for (int k0 = 0; k0 < DM; k0 += 32) {
        async16(ah + aoff0 + k0, lA0);
        async16(ah + aoff1 + k0, lA1);
        async16(wth + boff0 + k0, lB0);
        async16(wth + boff1 + k0, lB1);
        async16(wtl + boff0 + k0, lBl0);
        async16(wtl + boff1 + k0, lBl1);
        __syncthreads();

        f16x8 av[4], bvh[4], bvl[4];
#pragma unroll
        for (int t = 0; t < 4; ++t) {
            int ai  = ((((wr << 2) + t) << 6) + lane) << 3;
            int bi2 = ((((wc << 2) + t) << 6) + lane) << 3;
            av[t]  = *(const f16x8*)&Ah[ai];
            bvh[t] = *(const f16x8*)&Bh[bi2];
            bvl[t] = *(const f16x8*)&Bl[bi2];
        }
#pragma unroll
        for (int rt = 0; rt < 4; ++rt)
#pragma unroll
            for (int ct = 0; ct < 4; ++ct) {
                acc[rt][ct] = MFMAH(av[rt], bvl[ct], acc[rt][ct]);
                acc[rt][ct] = MFMAH(av[rt], bvh[ct], acc[rt][ct]);
            }
        __syncthreads();
    }

    // epilogue: LDS transpose -> coalesced float4 stores
    const int row0w = row0 + wr * 64;
    const int colw  = col0 + wc * 64;
    float bc[4];
#pragma unroll
    for (int ct = 0; ct < 4; ++ct) bc[ct] = bias[colw + (ct << 4) + m];

    float* tb = (float*)SM + wave * 1088;
    const int rr = lane >> 2, jj = lane & 3;
#pragma unroll
    for (int rt = 0; rt < 4; ++rt) {
#pragma unroll
        for (int ct = 0; ct < 4; ++ct)
#pragma unroll
            for (int rg = 0; rg < 4; ++rg)
                tb[((quad << 2) + rg) * 68 + (ct << 4) + m] =
                    acc[rt][ct][rg] + bc[ct];
        LGKM0();
        int n = row0w + (rt << 4) + rr;
#pragma unroll
        for (int i = 0; i < 4; ++i) {
            int c = (jj << 2) + (i << 4);
            *(float4*)&out[(size_t)n * DM + colw + c] =
                *(const float4*)&tb[rr * 68 + c];
        }
    }
}

// ---------------------------------------------------------------------------
extern "C" void kernel_launch(void* const* d_in, const int* in_sizes, int n_in,
                              void* d_out, int out_size, void* d_ws, size_t ws_size,
                              hipStream_t stream)
{
    const float* x    = (const float*)d_in[0];
    const float* Wqkv = (const float*)d_in[1];
    const float* bqkv = (const float*)d_in[2];
    const float* Wo   = (const float*)d_in[3];
    const float* bo   = (const float*)d_in[4];
    float* out = (float*)d_out;

    char* ws = (char*)d_ws;
    const size_t MB = 1024 * 1024;
    _Float16* qh    = (_Float16*)(ws);                       // 8 MB [B,H,S,64]
    _Float16* oh    = (_Float16*)(ws + 8 * MB);              // 8 MB [B,S,512]
    _Float16* kh    = (_Float16*)(ws + 16 * MB);             // 8 MB [B,H,S,64]
    _Float16* vT    = (_Float16*)(ws + 24 * MB);             // 8 MB [B,H,64,S]
    _Float16* xh    = (_Float16*)(ws + 32 * MB);             // 8 MB [8192][512]
    _Float16* wqt_h = (_Float16*)(ws + 40 * MB);             // 1.5 MB [1536][512]
    _Float16* wqt_l = (_Float16*)(ws + 40 * MB + 1536 * 1024);
    _Float16* wot_h = (_Float16*)(ws + 43 * MB);             // 0.5 MB [512][512]
    _Float16* wot_l = (_Float16*)(ws + 43 * MB + 512 * 1024);
    float2*   rtab  = (float2*)(ws + 44 * MB);               // 0.5 MB [2048][32]

    prep_all<<<2560, 256, 0, stream>>>(x, Wqkv, Wo, rtab, wqt_h, wqt_l,
                                       wot_h, wot_l, xh);
    qkv_mfma<<<dim3(64, 12), 256, 0, stream>>>(xh, wqt_h, wqt_l, bqkv, rtab,
                                               qh, kh, vT);
    attn_mfma<<<dim3(32, 32), 256, 0, stream>>>(qh, kh, vT, oh);
    out_mfma<<<dim3(64, 4), 256, 0, stream>>>(oh, wot_h, wot_l, bo, out);
}

// Round 7
// 195.634 us; speedup vs baseline: 1.5250x; 1.1059x over previous
//
#include <hip/hip_runtime.h>
#include <math.h>

// Problem constants: B=4, S=2048, D=512, H=8, Hd=64
#define SEQ 2048
#define DM 512
#define NH 8
#define HD 64

typedef _Float16 f16x8 __attribute__((ext_vector_type(8)));
typedef _Float16 f16x4 __attribute__((ext_vector_type(4)));
typedef __fp16 h16x2 __attribute__((ext_vector_type(2)));   // builtin ABI type
typedef float f32x4 __attribute__((ext_vector_type(4)));
#define MFMAH(A, B, C) __builtin_amdgcn_mfma_f32_16x16x32_f16(A, B, C, 0, 0, 0)

__device__ __forceinline__ void async16(const void* g, void* l) {
    __builtin_amdgcn_global_load_lds((__attribute__((address_space(1))) void*)g,
                                     (__attribute__((address_space(3))) void*)l,
                                     16, 0, 0);
}
#define LGKM0() asm volatile("s_waitcnt lgkmcnt(0)" ::: "memory")
#define WAITVM(n) asm volatile("s_waitcnt vmcnt(" #n ")" ::: "memory")
#define SB0() __builtin_amdgcn_sched_barrier(0)
// raw barrier (no implicit vmcnt/lgkmcnt drain) fenced against code motion
#define BAR() do { SB0(); __builtin_amdgcn_s_barrier(); SB0(); } while (0)

// native exp2 (scores bounded |s|<=~9: no edge cases, 1-ulp HW accuracy fine)
#if __has_builtin(__builtin_amdgcn_exp2f)
#define EXP2(x) __builtin_amdgcn_exp2f(x)
#else
#define EXP2(x) exp2f(x)
#endif

// scale = 1/sqrt(64) * log2(e), folded into q at the QKV epilogue;
// scores land in the log2 domain -> exp2, no max subtraction needed.
#define QSCALE 0.18033688011112042f

// ---------------------------------------------------------------------------
// Fused prep kernel (range-dispatched by blockIdx.x).
// ---------------------------------------------------------------------------
__global__ __launch_bounds__(256)
void prep_all(const float* __restrict__ x, const float* __restrict__ Wqkv,
              const float* __restrict__ Wo,
              float2* __restrict__ tab,
              _Float16* __restrict__ wqt_h, _Float16* __restrict__ wqt_l,
              _Float16* __restrict__ wot_h, _Float16* __restrict__ wot_l,
              _Float16* __restrict__ xh)
{
    __shared__ float T[64][65];
    const int bid = blockIdx.x;
    const int tid = threadIdx.x;

    if (bid < 256) {
        int idx = bid * 256 + tid;   // 65536
        int s = idx >> 5, p = idx & 31;
        const float c = -0.28782313662425572f;  // -ln(10000)/32
        float f = (float)s * expf(c * (float)p);
        float sn, cs;
        sincosf(f, &sn, &cs);
        tab[idx] = make_float2(cs, sn);
        return;
    }
    if (bid < 512) {
        const float* W;
        _Float16 *hi, *lo;
        int N, bx, by;
        if (bid < 448) {
            int b = bid - 256;                 // 192 blocks: 24 x 8
            bx = b % 24; by = b / 24;
            W = Wqkv; hi = wqt_h; lo = wqt_l; N = 3 * DM;
        } else {
            int b = bid - 448;                 // 64 blocks: 8 x 8
            bx = b % 8; by = b / 8;
            W = Wo; hi = wot_h; lo = wot_l; N = DM;
        }
        const int c0 = bx * 64, k0 = by * 64;
#pragma unroll
        for (int it = 0; it < 4; ++it) {
            int idx = it * 256 + tid;
            int r = idx >> 4, c4 = (idx & 15) << 2;
            *(float4*)&T[r][c4] = *(const float4*)&W[(size_t)(k0 + r) * N + c0 + c4];
        }
        __syncthreads();
#pragma unroll
        for (int it = 0; it < 4; ++it) {
            int idx = it * 256 + tid;
            int c = idx >> 4, k4 = (idx & 15) << 2;
            f16x4 hv, lv;
#pragma unroll
            for (int r = 0; r < 4; ++r) {
                float w = T[k4 + r][c];
                _Float16 h = (_Float16)w;
                hv[r] = h;
                lv[r] = (_Float16)(w - (float)h);
            }
            size_t off = (size_t)(c0 + c) * DM + k0 + k4;
            *(f16x4*)&hi[off] = hv;
            *(f16x4*)&lo[off] = lv;
        }
        return;
    }
    // x -> fp16 single
    size_t i = ((size_t)(bid - 512) * 256 + tid) << 3;
    float4 a0 = *(const float4*)&x[i];
    float4 a1 = *(const float4*)&x[i + 4];
    float fv[8] = {a0.x, a0.y, a0.z, a0.w, a1.x, a1.y, a1.z, a1.w};
    f16x8 hv;
#pragma unroll
    for (int j = 0; j < 8; ++j) hv[j] = (_Float16)fv[j];
    *(f16x8*)&xh[i] = hv;
}

// ---------------------------------------------------------------------------
// Kernel 1: QKV GEMM, 2-term fp16 MFMA (A=x single fp16, W split hi/lo).
// 128x128 tile, 4 waves. Epilogue: LDS transpose -> bias + RoPE.
// q: PRE-SCALED (QSCALE) fp16 [B,H,S,64]; k: fp16 [B,H,S,64];
// v: fp16 transposed [B,H,64,S].
// ---------------------------------------------------------------------------
__global__ __launch_bounds__(256)
void qkv_mfma(const _Float16* __restrict__ xh,
              const _Float16* __restrict__ wth, const _Float16* __restrict__ wtl,
              const float* __restrict__ bias, const float2* __restrict__ tab,
              _Float16* __restrict__ qo, _Float16* __restrict__ ko,
              _Float16* __restrict__ vo)
{
    __shared__ __align__(16) _Float16 SM[12288];    // 24 KB
    _Float16* Ah = SM;
    _Float16* Bh = SM + 4096;
    _Float16* Bl = SM + 8192;

    const int tid  = threadIdx.x;
    const int lane = tid & 63;
    const int wave = tid >> 6;
    const int quad = lane >> 4;
    const int m    = lane & 15;
    const int wr   = wave >> 1, wc = wave & 1;
    const int row0 = blockIdx.x * 128;
    const int by   = blockIdx.y;            // 0..11
    const int col0 = by * 128;

    const size_t aoff0 = (size_t)(row0 + wave * 16 + m) * DM + (quad << 3);
    const size_t aoff1 = (size_t)(row0 + (wave + 4) * 16 + m) * DM + (quad << 3);
    const size_t boff0 = (size_t)(col0 + wave * 16 + m) * DM + (quad << 3);
    const size_t boff1 = (size_t)(col0 + (wave + 4) * 16 + m) * DM + (quad << 3);
    _Float16* lA0 = &Ah[wave << 9];     _Float16* lA1 = &Ah[(wave + 4) << 9];
    _Float16* lB0 = &Bh[wave << 9];     _Float16* lB1 = &Bh[(wave + 4) << 9];
    _Float16* lBl0 = &Bl[wave << 9];    _Float16* lBl1 = &Bl[(wave + 4) << 9];

    f32x4 acc[4][4];
#pragma unroll
    for (int i = 0; i < 4; ++i)
#pragma unroll
        for (int j = 0; j < 4; ++j) acc[i][j] = (f32x4){0.f, 0.f, 0.f, 0.f};

    for (int k0 = 0; k0 < DM; k0 += 32) {
        async16(xh + aoff0 + k0, lA0);
        async16(xh + aoff1 + k0, lA1);
        async16(wth + boff0 + k0, lB0);
        async16(wth + boff1 + k0, lB1);
        async16(wtl + boff0 + k0, lBl0);
        async16(wtl + boff1 + k0, lBl1);
        __syncthreads();

        f16x8 av[4], bvh[4], bvl[4];
#pragma unroll
        for (int t = 0; t < 4; ++t) {
            int ai  = ((((wr << 2) + t) << 6) + lane) << 3;
            int bi2 = ((((wc << 2) + t) << 6) + lane) << 3;
            av[t]  = *(const f16x8*)&Ah[ai];
            bvh[t] = *(const f16x8*)&Bh[bi2];
            bvl[t] = *(const f16x8*)&Bl[bi2];
        }
#pragma unroll
        for (int rt = 0; rt < 4; ++rt)
#pragma unroll
            for (int ct = 0; ct < 4; ++ct) {
                acc[rt][ct] = MFMAH(av[rt], bvl[ct], acc[rt][ct]);
                acc[rt][ct] = MFMAH(av[rt], bvh[ct], acc[rt][ct]);
            }
        __syncthreads();
    }

    // ---- epilogue ----
    const int sel   = by >> 2;              // 0=q 1=k 2=v
    const int head  = ((by << 1) + wc) & 7;
    const int row0w = row0 + wr * 64;
    const int bidx  = row0w >> 11;
    const int s0    = row0w & (SEQ - 1);
    const int colw  = col0 + wc * 64;

    float bc[4];
#pragma unroll
    for (int ct = 0; ct < 4; ++ct) bc[ct] = bias[colw + (ct << 4) + m];

    if (sel == 2) {
        // v: direct transposed store [B,H,d,s], f16x4 along s
#pragma unroll
        for (int ct = 0; ct < 4; ++ct) {
            int d = (ct << 4) + m;
#pragma unroll
            for (int rt = 0; rt < 4; ++rt) {
                f32x4 a = acc[rt][ct];
                f16x4 ov;
#pragma unroll
                for (int rg = 0; rg < 4; ++rg) ov[rg] = (_Float16)(a[rg] + bc[ct]);
                size_t off = ((size_t)((bidx * NH + head) * HD + d)) * SEQ
                           + s0 + (rt << 4) + (quad << 2);
                *(f16x4*)&vo[off] = ov;
            }
        }
    } else {
        // q/k: per-wave LDS transpose + RoPE + fp16 vector stores
        const float sc = (sel == 0) ? QSCALE : 1.0f;
        _Float16* dh = (sel == 0) ? qo : ko;
        float* tb = (float*)SM + wave * 1088;       // 16 x 68 f32
        const int rr = lane >> 2, jj = lane & 3;
#pragma unroll
        for (int rt = 0; rt < 4; ++rt) {
#pragma unroll
            for (int ct = 0; ct < 4; ++ct)
#pragma unroll
                for (int rg = 0; rg < 4; ++rg)
                    tb[((quad << 2) + rg) * 68 + (ct << 4) + m] =
                        acc[rt][ct][rg] + bc[ct];
            LGKM0();
            int s = (row0w + (rt << 4) + rr) & (SEQ - 1);
#pragma unroll
            for (int i = 0; i < 4; ++i) {
                int c = (jj << 2) + (i << 4);
                float4 vv = *(const float4*)&tb[rr * 68 + c];
                float4 t4 = *(const float4*)&tab[(s << 5) + (c >> 1)];
                f16x4 hv;
                hv[0] = (_Float16)((vv.x * t4.x - vv.y * t4.y) * sc);
                hv[1] = (_Float16)((vv.x * t4.y + vv.y * t4.x) * sc);
                hv[2] = (_Float16)((vv.z * t4.z - vv.w * t4.w) * sc);
                hv[3] = (_Float16)((vv.z * t4.w + vv.w * t4.z) * sc);
                size_t off = (((size_t)(bidx * NH + head) * SEQ + s) << 6) + c;
                *(f16x4*)&dh[off] = hv;
            }
        }
    }
}

// ---------------------------------------------------------------------------
// Kernel 2: fp16 MFMA flash attention — 128 q/block, 32 q/wave (2 groups).
// R6 diagnosis: all pipes <25%, three schedules identical at ~75 µs ->
// LDS-issue-throughput bound (~240 LDS cyc per 16-q wave-tile, 51 µs/CU
// floor). Fix: each wave computes TWO 16-q groups sharing every K/V LDS
// fragment read (kf read once -> 2 QK MFMAs; V read once -> 2 PV MFMAs).
// Per-q LDS traffic drops 1.7x -> floor ~31 µs.
//   - Grid 512 blocks (2/CU); LDS 48 KB = 16K KH + 16K VF + 16K PW.
//   - __launch_bounds__(256,2): the old (256,4) capped VGPR at 64; the
//     2-group version needs ~120.
//   - XCD swizzle (R5/R6-validated: FETCH 69.7->12.3 MB), remapped for
//     512 blocks: 4 bh per XCD, K/V working set 2 MB < 4 MB L2.
//   - KVBLK=128 staging, rotated PW transform, cvt_pkrtz+fdot2, native
//     exp2 — all validated in R4/R6.
// ---------------------------------------------------------------------------
__global__ __launch_bounds__(256, 2)
void attn_mfma(const _Float16* __restrict__ qh_, const _Float16* __restrict__ kh_,
               const _Float16* __restrict__ vt, _Float16* __restrict__ oh)
{
    __shared__ __align__(16) _Float16 KH[8192];     // 2 tiles x 8 KB
    __shared__ __align__(16) _Float16 VF[8192];     // 2 tiles x 8 KB
    __shared__ __align__(16) _Float16 PW[4][2048];  // per wave 2 x (16 x 64)

    const int tid  = threadIdx.x;
    const int lane = tid & 63;
    const int wave = tid >> 6;
    const int m    = lane & 15;
    const int quad = lane >> 4;

    // XCD-bijective swizzle: 512 blocks, xcd = linear&7 (round-robin);
    // bh = xcd + 8*(idx>>4): each XCD hosts 4 bh x 16 q-tiles.
    const int l   = blockIdx.x + (blockIdx.y << 4);
    const int idx = l >> 3;
    const int bh  = (l & 7) + ((idx >> 4) << 3);   // 0..31
    const int qt  = idx & 15;                      // 0..15 (128-q tiles)
    const int bi = bh >> 3, h = bh & 7;

    const _Float16* qhp = qh_ + ((size_t)bh * SEQ + qt * 128 + wave * 16) * HD;
    const _Float16* khp = kh_ + (size_t)bh * SEQ * HD;
    const _Float16* vp  = vt  + (size_t)bh * HD * SEQ;

    // Q B-frags, two groups 64 rows apart (pre-scaled by QSCALE)
    f16x8 qfa[2], qfb[2];
#pragma unroll
    for (int c = 0; c < 2; ++c) {
        qfa[c] = *(const f16x8*)&qhp[((size_t)m << 6) + c * 32 + (quad << 3)];
        qfb[c] = *(const f16x8*)&qhp[4096 + ((size_t)m << 6) + c * 32 + (quad << 3)];
    }

    f32x4 oacca[4], oaccb[4];   // [dt]: D[q=quad*4+rg][d=dt*16+m]
#pragma unroll
    for (int dt = 0; dt < 4; ++dt) {
        oacca[dt] = (f32x4){0.f, 0.f, 0.f, 0.f};
        oaccb[dt] = (f32x4){0.f, 0.f, 0.f, 0.f};
    }
    float la1 = 0.f, la2 = 0.f, lb1 = 0.f, lb2 = 0.f;

    // staging offsets: wave w stages K keys w*16+m and V rows d=w*16+m
    const size_t koff0 = ((size_t)(wave * 16 + m) << 6) + (quad << 3);
    const size_t koff1 = koff0 + 32;
    const size_t voff0 = ((size_t)(wave * 16 + m) << 11) + (quad << 3);
    const size_t voff1 = voff0 + 32;

    const h16x2 ones = {(__fp16)1.f, (__fp16)1.f};
    _Float16* pwa = PW[wave];
    _Float16* pwb = PW[wave] + 1024;
    const int rot = m << 2;          // per-row key rotation (multiple of 4)

    auto tile = [&](const _Float16* KB, const _Float16* VB) {
        // ---- S^T = K·Q^T for both q-groups; kf read ONCE per pair ----
        f32x4 sva[4], svb[4];
#pragma unroll
        for (int nt = 0; nt < 4; ++nt) {
            f32x4 sa = (f32x4){0.f, 0.f, 0.f, 0.f};
            f32x4 sb = (f32x4){0.f, 0.f, 0.f, 0.f};
#pragma unroll
            for (int c = 0; c < 2; ++c) {
                f16x8 kf = *(const f16x8*)&KB[((c * 4 + nt) * 64 + lane) << 3];
                sa = MFMAH(kf, qfa[c], sa);
                sb = MFMAH(kf, qfb[c], sb);
            }
            sva[nt] = sa;   // [key=nt*16+quad*4+rg][q=m], log2 domain
            svb[nt] = sb;
        }

        // ---- V to regs (read ONCE, feeds both groups' PV) ----
        f16x8 vr0[4], vr1[4];
#pragma unroll
        for (int dt = 0; dt < 4; ++dt) {
            vr0[dt] = *(const f16x8*)&VB[((0 * 4 + dt) * 64 + lane) << 3];
            vr1[dt] = *(const f16x8*)&VB[((1 * 4 + dt) * 64 + lane) << 3];
        }

        // ---- softmax + pack + rotated PW write, both groups ----
#pragma unroll
        for (int nt = 0; nt < 4; ++nt) {
            union { unsigned int u[2]; f16x4 v; } pka, pkb;
#pragma unroll
            for (int i = 0; i < 2; ++i) {
                h16x2 ta = __builtin_amdgcn_cvt_pkrtz(EXP2(sva[nt][2 * i]),
                                                      EXP2(sva[nt][2 * i + 1]));
                h16x2 tb = __builtin_amdgcn_cvt_pkrtz(EXP2(svb[nt][2 * i]),
                                                      EXP2(svb[nt][2 * i + 1]));
                if (i == 0) { la1 = __builtin_amdgcn_fdot2(ta, ones, la1, false);
                              lb1 = __builtin_amdgcn_fdot2(tb, ones, lb1, false); }
                else        { la2 = __builtin_amdgcn_fdot2(ta, ones, la2, false);
                              lb2 = __builtin_amdgcn_fdot2(tb, ones, lb2, false); }
                union { h16x2 hh; unsigned int uu; } ca, cb;
                ca.hh = ta; cb.hh = tb;
                pka.u[i] = ca.uu; pkb.u[i] = cb.uu;
            }
            int pos = ((nt << 4) + (quad << 2) + rot) & 63;
            *(f16x4*)&pwa[(m << 6) + pos] = pka.v;
            *(f16x4*)&pwb[(m << 6) + pos] = pkb.v;
        }
        LGKM0();
        union { f16x4 h4[2]; f16x8 w; } a0, a1, b0, b1;
        a0.h4[0] = *(const f16x4*)&pwa[(m << 6) + (((quad << 3) + rot) & 63)];
        a0.h4[1] = *(const f16x4*)&pwa[(m << 6) + (((quad << 3) + 4 + rot) & 63)];
        a1.h4[0] = *(const f16x4*)&pwa[(m << 6) + ((32 + (quad << 3) + rot) & 63)];
        a1.h4[1] = *(const f16x4*)&pwa[(m << 6) + ((36 + (quad << 3) + rot) & 63)];
        b0.h4[0] = *(const f16x4*)&pwb[(m << 6) + (((quad << 3) + rot) & 63)];
        b0.h4[1] = *(const f16x4*)&pwb[(m << 6) + (((quad << 3) + 4 + rot) & 63)];
        b1.h4[0] = *(const f16x4*)&pwb[(m << 6) + ((32 + (quad << 3) + rot) & 63)];
        b1.h4[1] = *(const f16x4*)&pwb[(m << 6) + ((36 + (quad << 3) + rot) & 63)];

        // ---- O += P·V, both groups from the same V regs ----
#pragma unroll
        for (int dt = 0; dt < 4; ++dt) {
            oacca[dt] = MFMAH(a0.w, vr0[dt], oacca[dt]);
            oacca[dt] = MFMAH(a1.w, vr1[dt], oacca[dt]);
            oaccb[dt] = MFMAH(b0.w, vr0[dt], oaccb[dt]);
            oaccb[dt] = MFMAH(b1.w, vr1[dt], oaccb[dt]);
        }
    };

    // ---- main loop: 16 super-tiles of 128 keys, single-buffered ----
#pragma unroll 1
    for (int st = 0; st < SEQ / 128; ++st) {
        const size_t t0 = (size_t)st * 2;
        BAR();                       // all reads of previous super-tile done
        async16(khp + koff0 + (t0 << 12), &KH[wave << 9]);
        async16(khp + koff1 + (t0 << 12), &KH[(wave + 4) << 9]);
        async16(khp + koff0 + ((t0 + 1) << 12), &KH[4096 + (wave << 9)]);
        async16(khp + koff1 + ((t0 + 1) << 12), &KH[4096 + ((wave + 4) << 9)]);
        async16(vp + voff0 + (t0 << 6), &VF[wave << 9]);
        async16(vp + voff1 + (t0 << 6), &VF[(wave + 4) << 9]);
        async16(vp + voff0 + ((t0 + 1) << 6), &VF[4096 + (wave << 9)]);
        async16(vp + voff1 + ((t0 + 1) << 6), &VF[4096 + ((wave + 4) << 9)]);
        WAITVM(0);                   // my stages landed
        BAR();                       // everyone's stages landed
        tile(&KH[0], &VF[0]);
        tile(&KH[4096], &VF[4096]);
    }

    // ---- epilogue: per-group l reduce, normalize, fp16 store ----
#pragma unroll
    for (int g = 0; g < 2; ++g) {
        float lr = (g == 0) ? (la1 + la2) : (lb1 + lb2);
        lr += __shfl_xor(lr, 16);
        lr += __shfl_xor(lr, 32);
        float inv = 1.0f / lr;
        f32x4* oa = (g == 0) ? oacca : oaccb;
        size_t ob = ((size_t)(bi * SEQ + qt * 128 + g * 64 + wave * 16
                              + (quad << 2))) * DM + h * HD + m;
#pragma unroll
        for (int rg = 0; rg < 4; ++rg) {
            float il = __shfl(inv, (quad << 2) + rg, 16);
#pragma unroll
            for (int dt = 0; dt < 4; ++dt)
                oh[ob + (size_t)rg * DM + dt * 16] = (_Float16)(oa[dt][rg] * il);
        }
    }
}

// ---------------------------------------------------------------------------
// Kernel 3: out = attn @ Wo + bo, 2-term fp16 MFMA (A single, W hi/lo).
// ---------------------------------------------------------------------------
__global__ __launch_bounds__(256)
void out_mfma(const _Float16* __restrict__ ah,
              const _Float16* __restrict__ wth, const _Float16* __restrict__ wtl,
              const float* __restrict__ bias, float* __restrict__ out)
{
    __shared__ __align__(16) _Float16 SM[12288];
    _Float16* Ah = SM;
    _Float16* Bh = SM + 4096;
    _Float16* Bl = SM + 8192;

    const int tid  = threadIdx.x;
    const int lane = tid & 63;
    const int wave = tid >> 6;
    const int quad = lane >> 4;
    const int m    = lane & 15;
    const int wr   = wave >> 1, wc = wave & 1;
    const int row0 = blockIdx.x * 128;
    const int col0 = blockIdx.y * 128;

    const size_t aoff0 = (size_t)(row0 + wave * 16 + m) * DM + (quad << 3);
    const size_t aoff1 = (size_t)(row0 + (wave + 4) * 16 + m) * DM + (quad << 3);
    const size_t boff0 = (size_t)(col0 + wave * 16 + m) * DM + (quad << 3);
    const size_t boff1 = (size_t)(col0 + (wave + 4) * 16 + m) * DM + (quad << 3);
    _Float16* lA0 = &Ah[wave << 9];     _Float16* lA1 = &Ah[(wave + 4) << 9];
    _Float16* lB0 = &Bh[wave << 9];     _Float16* lB1 = &Bh[(wave + 4) << 9];
    _Float16* lBl0 = &Bl[wave << 9];    _Float16* lBl1 = &Bl[(wave + 4) << 9];

    f32x4 acc[4][4];
#pragma unroll
    for (int i = 0; i < 4; ++i)
#pragma unroll
        for (int j = 0; j < 4; ++j) acc[i][j] = (f32x4){0.f, 0.f, 0.f, 0.f};

    for (int k0 = 0; k0 < DM; k0 += 32) {
        async16(ah + aoff0 + k0, lA0);
        async16(ah + aoff1 + k0, lA1);
        async16(wth + boff0 + k0, lB0);
        async16(wth + boff1 + k0, lB1);
        async16(wtl + boff0 + k0, lBl0);
        async16(wtl + boff1 + k0, lBl1);
        __syncthreads();

        f16x8 av[4], bvh[4], bvl[4];
#pragma unroll
        for (int t = 0; t < 4; ++t) {
            int ai  = ((((wr << 2) + t) << 6) + lane) << 3;
            int bi2 = ((((wc << 2) + t) << 6) + lane) << 3;
            av[t]  = *(const f16x8*)&Ah[ai];
            bvh[t] = *(const f16x8*)&Bh[bi2];
            bvl[t] = *(const f16x8*)&Bl[bi2];
        }
#pragma unroll
        for (int rt = 0; rt < 4; ++rt)
#pragma unroll
            for (int ct = 0; ct < 4; ++ct) {
                acc[rt][ct] = MFMAH(av[rt], bvl[ct], acc[rt][ct]);
                acc[rt][ct] = MFMAH(av[rt], bvh[ct], acc[rt][ct]);
            }
        __syncthreads();
    }

    // epilogue: LDS transpose -> coalesced float4 stores
    const int row0w = row0 + wr * 64;
    const int colw  = col0 + wc * 64;
    float bc[4];
#pragma unroll
    for (int ct = 0; ct < 4; ++ct) bc[ct] = bias[colw + (ct << 4) + m];

    float* tb = (float*)SM + wave * 1088;
    const int rr = lane >> 2, jj = lane & 3;
#pragma unroll
    for (int rt = 0; rt < 4; ++rt) {
#pragma unroll
        for (int ct = 0; ct < 4; ++ct)
#pragma unroll
            for (int rg = 0; rg < 4; ++rg)
                tb[((quad << 2) + rg) * 68 + (ct << 4) + m] =
                    acc[rt][ct][rg] + bc[ct];
        LGKM0();
        int n = row0w + (rt << 4) + rr;
#pragma unroll
        for (int i = 0; i < 4; ++i) {
            int c = (jj << 2) + (i << 4);
            *(float4*)&out[(size_t)n * DM + colw + c] =
                *(const float4*)&tb[rr * 68 + c];
        }
    }
}

// ---------------------------------------------------------------------------
extern "C" void kernel_launch(void* const* d_in, const int* in_sizes, int n_in,
                              void* d_out, int out_size, void* d_ws, size_t ws_size,
                              hipStream_t stream)
{
    const float* x    = (const float*)d_in[0];
    const float* Wqkv = (const float*)d_in[1];
    const float* bqkv = (const float*)d_in[2];
    const float* Wo   = (const float*)d_in[3];
    const float* bo   = (const float*)d_in[4];
    float* out = (float*)d_out;

    char* ws = (char*)d_ws;
    const size_t MB = 1024 * 1024;
    _Float16* qh    = (_Float16*)(ws);                       // 8 MB [B,H,S,64]
    _Float16* oh    = (_Float16*)(ws + 8 * MB);              // 8 MB [B,S,512]
    _Float16* kh    = (_Float16*)(ws + 16 * MB);             // 8 MB [B,H,S,64]
    _Float16* vT    = (_Float16*)(ws + 24 * MB);             // 8 MB [B,H,64,S]
    _Float16* xh    = (_Float16*)(ws + 32 * MB);             // 8 MB [8192][512]
    _Float16* wqt_h = (_Float16*)(ws + 40 * MB);             // 1.5 MB [1536][512]
    _Float16* wqt_l = (_Float16*)(ws + 40 * MB + 1536 * 1024);
    _Float16* wot_h = (_Float16*)(ws + 43 * MB);             // 0.5 MB [512][512]
    _Float16* wot_l = (_Float16*)(ws + 43 * MB + 512 * 1024);
    float2*   rtab  = (float2*)(ws + 44 * MB);               // 0.5 MB [2048][32]

    prep_all<<<2560, 256, 0, stream>>>(x, Wqkv, Wo, rtab, wqt_h, wqt_l,
                                       wot_h, wot_l, xh);
    qkv_mfma<<<dim3(64, 12), 256, 0, stream>>>(xh, wqt_h, wqt_l, bqkv, rtab,
                                               qh, kh, vT);
    attn_mfma<<<dim3(16, 32), 256, 0, stream>>>(qh, kh, vT, oh);
    out_mfma<<<dim3(64, 4), 256, 0, stream>>>(oh, wot_h, wot_l, bo, out);
}

// Round 8
// 177.762 us; speedup vs baseline: 1.6784x; 1.1005x over previous
//
#include <hip/hip_runtime.h>
#include <math.h>

// Problem constants: B=4, S=2048, D=512, H=8, Hd=64
#define SEQ 2048
#define DM 512
#define NH 8
#define HD 64

typedef _Float16 f16x8 __attribute__((ext_vector_type(8)));
typedef _Float16 f16x4 __attribute__((ext_vector_type(4)));
typedef __fp16 h16x2 __attribute__((ext_vector_type(2)));   // builtin ABI type
typedef float f32x4 __attribute__((ext_vector_type(4)));
#define MFMAH(A, B, C) __builtin_amdgcn_mfma_f32_16x16x32_f16(A, B, C, 0, 0, 0)

__device__ __forceinline__ void async16(const void* g, void* l) {
    __builtin_amdgcn_global_load_lds((__attribute__((address_space(1))) void*)g,
                                     (__attribute__((address_space(3))) void*)l,
                                     16, 0, 0);
}
#define LGKM0() asm volatile("s_waitcnt lgkmcnt(0)" ::: "memory")
#define WAITVM(n) asm volatile("s_waitcnt vmcnt(" #n ")" ::: "memory")
#define SB0() __builtin_amdgcn_sched_barrier(0)
// raw barrier (no implicit vmcnt/lgkmcnt drain) fenced against code motion
#define BAR() do { SB0(); __builtin_amdgcn_s_barrier(); SB0(); } while (0)

// native exp2 (scores bounded |s|<=~9: no edge cases, 1-ulp HW accuracy fine)
#if __has_builtin(__builtin_amdgcn_exp2f)
#define EXP2(x) __builtin_amdgcn_exp2f(x)
#else
#define EXP2(x) exp2f(x)
#endif

// scale = 1/sqrt(64) * log2(e), folded into q at the QKV epilogue;
// scores land in the log2 domain -> exp2, no max subtraction needed.
#define QSCALE 0.18033688011112042f

// ---------------------------------------------------------------------------
// Fused prep kernel (range-dispatched by blockIdx.x).
// Single-term W now: A (xh) is fp16-rounded anyway (2^-11), and q/k/v/P/oh
// are all fp16 downstream — the old lo-term's 2^-22 W precision was below
// the pipeline's noise floor. Error budget: +~3e-4 std vs 4.88e-3 threshold.
// ---------------------------------------------------------------------------
__global__ __launch_bounds__(256)
void prep_all(const float* __restrict__ x, const float* __restrict__ Wqkv,
              const float* __restrict__ Wo,
              float2* __restrict__ tab,
              _Float16* __restrict__ wqt_h, _Float16* __restrict__ wot_h,
              _Float16* __restrict__ xh)
{
    __shared__ float T[64][65];
    const int bid = blockIdx.x;
    const int tid = threadIdx.x;

    if (bid < 256) {
        int idx = bid * 256 + tid;   // 65536
        int s = idx >> 5, p = idx & 31;
        const float c = -0.28782313662425572f;  // -ln(10000)/32
        float f = (float)s * expf(c * (float)p);
        float sn, cs;
        sincosf(f, &sn, &cs);
        tab[idx] = make_float2(cs, sn);
        return;
    }
    if (bid < 512) {
        const float* W;
        _Float16 *hi;
        int N, bx, by;
        if (bid < 448) {
            int b = bid - 256;                 // 192 blocks: 24 x 8
            bx = b % 24; by = b / 24;
            W = Wqkv; hi = wqt_h; N = 3 * DM;
        } else {
            int b = bid - 448;                 // 64 blocks: 8 x 8
            bx = b % 8; by = b / 8;
            W = Wo; hi = wot_h; N = DM;
        }
        const int c0 = bx * 64, k0 = by * 64;
#pragma unroll
        for (int it = 0; it < 4; ++it) {
            int idx = it * 256 + tid;
            int r = idx >> 4, c4 = (idx & 15) << 2;
            *(float4*)&T[r][c4] = *(const float4*)&W[(size_t)(k0 + r) * N + c0 + c4];
        }
        __syncthreads();
#pragma unroll
        for (int it = 0; it < 4; ++it) {
            int idx = it * 256 + tid;
            int c = idx >> 4, k4 = (idx & 15) << 2;
            f16x4 hv;
#pragma unroll
            for (int r = 0; r < 4; ++r)
                hv[r] = (_Float16)T[k4 + r][c];
            *(f16x4*)&hi[(size_t)(c0 + c) * DM + k0 + k4] = hv;
        }
        return;
    }
    // x -> fp16 single
    size_t i = ((size_t)(bid - 512) * 256 + tid) << 3;
    float4 a0 = *(const float4*)&x[i];
    float4 a1 = *(const float4*)&x[i + 4];
    float fv[8] = {a0.x, a0.y, a0.z, a0.w, a1.x, a1.y, a1.z, a1.w};
    f16x8 hv;
#pragma unroll
    for (int j = 0; j < 8; ++j) hv[j] = (_Float16)fv[j];
    *(f16x8*)&xh[i] = hv;
}

// ---------------------------------------------------------------------------
// Kernel 1: QKV GEMM, single-term fp16 MFMA.
// Row-colocated XCD swizzle (round-robin xcd = linear&7, validated R5/R6):
// XCD x owns row-blocks 8x..8x+7 -> its xh slice (1 MB) + the FULL wqt_h
// (1.5 MB) both fit the 4 MB per-XCD L2 -> steady-state A+B traffic is
// L2-local (4.3 TB/s/XCD, ~200cy) instead of L3 (~5 TB/s device-wide,
// ~600cy) — R7 counters showed qkv at the L3 ceiling with occupancy 14.5%.
// ---------------------------------------------------------------------------
__global__ __launch_bounds__(256)
void qkv_mfma(const _Float16* __restrict__ xh,
              const _Float16* __restrict__ wth,
              const float* __restrict__ bias, const float2* __restrict__ tab,
              _Float16* __restrict__ qo, _Float16* __restrict__ ko,
              _Float16* __restrict__ vo)
{
    __shared__ __align__(16) _Float16 SM[12288];    // 24 KB (epilogue needs 17.4K)
    _Float16* Ah = SM;
    _Float16* Bh = SM + 4096;

    const int tid  = threadIdx.x;
    const int lane = tid & 63;
    const int wave = tid >> 6;
    const int quad = lane >> 4;
    const int m    = lane & 15;
    const int wr   = wave >> 1, wc = wave & 1;

    // swizzle: linear id -> (rowblk, by) with row-colocation per XCD
    const int linear = blockIdx.x + (blockIdx.y << 6);   // 0..767
    const int xcd = linear & 7;
    const int r   = linear >> 3;                         // 0..95
    const int row0 = ((xcd << 3) + r / 12) * 128;
    const int by   = r % 12;
    const int col0 = by * 128;

    const size_t aoff0 = (size_t)(row0 + wave * 16 + m) * DM + (quad << 3);
    const size_t aoff1 = (size_t)(row0 + (wave + 4) * 16 + m) * DM + (quad << 3);
    const size_t boff0 = (size_t)(col0 + wave * 16 + m) * DM + (quad << 3);
    const size_t boff1 = (size_t)(col0 + (wave + 4) * 16 + m) * DM + (quad << 3);
    _Float16* lA0 = &Ah[wave << 9];     _Float16* lA1 = &Ah[(wave + 4) << 9];
    _Float16* lB0 = &Bh[wave << 9];     _Float16* lB1 = &Bh[(wave + 4) << 9];

    f32x4 acc[4][4];
#pragma unroll
    for (int i = 0; i < 4; ++i)
#pragma unroll
        for (int j = 0; j < 4; ++j) acc[i][j] = (f32x4){0.f, 0.f, 0.f, 0.f};

    for (int k0 = 0; k0 < DM; k0 += 32) {
        async16(xh + aoff0 + k0, lA0);
        async16(xh + aoff1 + k0, lA1);
        async16(wth + boff0 + k0, lB0);
        async16(wth + boff1 + k0, lB1);
        __syncthreads();

        f16x8 av[4], bvh[4];
#pragma unroll
        for (int t = 0; t < 4; ++t) {
            int ai  = ((((wr << 2) + t) << 6) + lane) << 3;
            int bi2 = ((((wc << 2) + t) << 6) + lane) << 3;
            av[t]  = *(const f16x8*)&Ah[ai];
            bvh[t] = *(const f16x8*)&Bh[bi2];
        }
#pragma unroll
        for (int rt = 0; rt < 4; ++rt)
#pragma unroll
            for (int ct = 0; ct < 4; ++ct)
                acc[rt][ct] = MFMAH(av[rt], bvh[ct], acc[rt][ct]);
        __syncthreads();
    }

    // ---- epilogue ----
    const int sel   = by >> 2;              // 0=q 1=k 2=v
    const int head  = ((by << 1) + wc) & 7;
    const int row0w = row0 + wr * 64;
    const int bidx  = row0w >> 11;
    const int s0    = row0w & (SEQ - 1);
    const int colw  = col0 + wc * 64;

    float bc[4];
#pragma unroll
    for (int ct = 0; ct < 4; ++ct) bc[ct] = bias[colw + (ct << 4) + m];

    if (sel == 2) {
        // v: direct transposed store [B,H,d,s], f16x4 along s
#pragma unroll
        for (int ct = 0; ct < 4; ++ct) {
            int d = (ct << 4) + m;
#pragma unroll
            for (int rt = 0; rt < 4; ++rt) {
                f32x4 a = acc[rt][ct];
                f16x4 ov;
#pragma unroll
                for (int rg = 0; rg < 4; ++rg) ov[rg] = (_Float16)(a[rg] + bc[ct]);
                size_t off = ((size_t)((bidx * NH + head) * HD + d)) * SEQ
                           + s0 + (rt << 4) + (quad << 2);
                *(f16x4*)&vo[off] = ov;
            }
        }
    } else {
        // q/k: per-wave LDS transpose + RoPE + fp16 vector stores
        const float sc = (sel == 0) ? QSCALE : 1.0f;
        _Float16* dh = (sel == 0) ? qo : ko;
        float* tb = (float*)SM + wave * 1088;       // 16 x 68 f32
        const int rr = lane >> 2, jj = lane & 3;
#pragma unroll
        for (int rt = 0; rt < 4; ++rt) {
#pragma unroll
            for (int ct = 0; ct < 4; ++ct)
#pragma unroll
                for (int rg = 0; rg < 4; ++rg)
                    tb[((quad << 2) + rg) * 68 + (ct << 4) + m] =
                        acc[rt][ct][rg] + bc[ct];
            LGKM0();
            int s = (row0w + (rt << 4) + rr) & (SEQ - 1);
#pragma unroll
            for (int i = 0; i < 4; ++i) {
                int c = (jj << 2) + (i << 4);
                float4 vv = *(const float4*)&tb[rr * 68 + c];
                float4 t4 = *(const float4*)&tab[(s << 5) + (c >> 1)];
                f16x4 hv;
                hv[0] = (_Float16)((vv.x * t4.x - vv.y * t4.y) * sc);
                hv[1] = (_Float16)((vv.x * t4.y + vv.y * t4.x) * sc);
                hv[2] = (_Float16)((vv.z * t4.z - vv.w * t4.w) * sc);
                hv[3] = (_Float16)((vv.z * t4.w + vv.w * t4.z) * sc);
                size_t off = (((size_t)(bidx * NH + head) * SEQ + s) << 6) + c;
                *(f16x4*)&dh[off] = hv;
            }
        }
    }
}

// ---------------------------------------------------------------------------
// Kernel 2: fp16 MFMA flash attention — UNCHANGED from R7 (validated win:
// 79 -> 56.8 µs, bank conflicts 0). 128 q/block, 32 q/wave (2 groups
// sharing every K/V LDS fragment read).
// ---------------------------------------------------------------------------
__global__ __launch_bounds__(256, 2)
void attn_mfma(const _Float16* __restrict__ qh_, const _Float16* __restrict__ kh_,
               const _Float16* __restrict__ vt, _Float16* __restrict__ oh)
{
    __shared__ __align__(16) _Float16 KH[8192];     // 2 tiles x 8 KB
    __shared__ __align__(16) _Float16 VF[8192];     // 2 tiles x 8 KB
    __shared__ __align__(16) _Float16 PW[4][2048];  // per wave 2 x (16 x 64)

    const int tid  = threadIdx.x;
    const int lane = tid & 63;
    const int wave = tid >> 6;
    const int m    = lane & 15;
    const int quad = lane >> 4;

    // XCD-bijective swizzle: 512 blocks, xcd = linear&7 (round-robin);
    // bh = xcd + 8*(idx>>4): each XCD hosts 4 bh x 16 q-tiles.
    const int l   = blockIdx.x + (blockIdx.y << 4);
    const int idx = l >> 3;
    const int bh  = (l & 7) + ((idx >> 4) << 3);   // 0..31
    const int qt  = idx & 15;                      // 0..15 (128-q tiles)
    const int bi = bh >> 3, h = bh & 7;

    const _Float16* qhp = qh_ + ((size_t)bh * SEQ + qt * 128 + wave * 16) * HD;
    const _Float16* khp = kh_ + (size_t)bh * SEQ * HD;
    const _Float16* vp  = vt  + (size_t)bh * HD * SEQ;

    // Q B-frags, two groups 64 rows apart (pre-scaled by QSCALE)
    f16x8 qfa[2], qfb[2];
#pragma unroll
    for (int c = 0; c < 2; ++c) {
        qfa[c] = *(const f16x8*)&qhp[((size_t)m << 6) + c * 32 + (quad << 3)];
        qfb[c] = *(const f16x8*)&qhp[4096 + ((size_t)m << 6) + c * 32 + (quad << 3)];
    }

    f32x4 oacca[4], oaccb[4];   // [dt]: D[q=quad*4+rg][d=dt*16+m]
#pragma unroll
    for (int dt = 0; dt < 4; ++dt) {
        oacca[dt] = (f32x4){0.f, 0.f, 0.f, 0.f};
        oaccb[dt] = (f32x4){0.f, 0.f, 0.f, 0.f};
    }
    float la1 = 0.f, la2 = 0.f, lb1 = 0.f, lb2 = 0.f;

    // staging offsets: wave w stages K keys w*16+m and V rows d=w*16+m
    const size_t koff0 = ((size_t)(wave * 16 + m) << 6) + (quad << 3);
    const size_t koff1 = koff0 + 32;
    const size_t voff0 = ((size_t)(wave * 16 + m) << 11) + (quad << 3);
    const size_t voff1 = voff0 + 32;

    const h16x2 ones = {(__fp16)1.f, (__fp16)1.f};
    _Float16* pwa = PW[wave];
    _Float16* pwb = PW[wave] + 1024;
    const int rot = m << 2;          // per-row key rotation (multiple of 4)

    auto tile = [&](const _Float16* KB, const _Float16* VB) {
        // ---- S^T = K·Q^T for both q-groups; kf read ONCE per pair ----
        f32x4 sva[4], svb[4];
#pragma unroll
        for (int nt = 0; nt < 4; ++nt) {
            f32x4 sa = (f32x4){0.f, 0.f, 0.f, 0.f};
            f32x4 sb = (f32x4){0.f, 0.f, 0.f, 0.f};
#pragma unroll
            for (int c = 0; c < 2; ++c) {
                f16x8 kf = *(const f16x8*)&KB[((c * 4 + nt) * 64 + lane) << 3];
                sa = MFMAH(kf, qfa[c], sa);
                sb = MFMAH(kf, qfb[c], sb);
            }
            sva[nt] = sa;   // [key=nt*16+quad*4+rg][q=m], log2 domain
            svb[nt] = sb;
        }

        // ---- V to regs (read ONCE, feeds both groups' PV) ----
        f16x8 vr0[4], vr1[4];
#pragma unroll
        for (int dt = 0; dt < 4; ++dt) {
            vr0[dt] = *(const f16x8*)&VB[((0 * 4 + dt) * 64 + lane) << 3];
            vr1[dt] = *(const f16x8*)&VB[((1 * 4 + dt) * 64 + lane) << 3];
        }

        // ---- softmax + pack + rotated PW write, both groups ----
#pragma unroll
        for (int nt = 0; nt < 4; ++nt) {
            union { unsigned int u[2]; f16x4 v; } pka, pkb;
#pragma unroll
            for (int i = 0; i < 2; ++i) {
                h16x2 ta = __builtin_amdgcn_cvt_pkrtz(EXP2(sva[nt][2 * i]),
                                                      EXP2(sva[nt][2 * i + 1]));
                h16x2 tb = __builtin_amdgcn_cvt_pkrtz(EXP2(svb[nt][2 * i]),
                                                      EXP2(svb[nt][2 * i + 1]));
                if (i == 0) { la1 = __builtin_amdgcn_fdot2(ta, ones, la1, false);
                              lb1 = __builtin_amdgcn_fdot2(tb, ones, lb1, false); }
                else        { la2 = __builtin_amdgcn_fdot2(ta, ones, la2, false);
                              lb2 = __builtin_amdgcn_fdot2(tb, ones, lb2, false); }
                union { h16x2 hh; unsigned int uu; } ca, cb;
                ca.hh = ta; cb.hh = tb;
                pka.u[i] = ca.uu; pkb.u[i] = cb.uu;
            }
            int pos = ((nt << 4) + (quad << 2) + rot) & 63;
            *(f16x4*)&pwa[(m << 6) + pos] = pka.v;
            *(f16x4*)&pwb[(m << 6) + pos] = pkb.v;
        }
        LGKM0();
        union { f16x4 h4[2]; f16x8 w; } a0, a1, b0, b1;
        a0.h4[0] = *(const f16x4*)&pwa[(m << 6) + (((quad << 3) + rot) & 63)];
        a0.h4[1] = *(const f16x4*)&pwa[(m << 6) + (((quad << 3) + 4 + rot) & 63)];
        a1.h4[0] = *(const f16x4*)&pwa[(m << 6) + ((32 + (quad << 3) + rot) & 63)];
        a1.h4[1] = *(const f16x4*)&pwa[(m << 6) + ((36 + (quad << 3) + rot) & 63)];
        b0.h4[0] = *(const f16x4*)&pwb[(m << 6) + (((quad << 3) + rot) & 63)];
        b0.h4[1] = *(const f16x4*)&pwb[(m << 6) + (((quad << 3) + 4 + rot) & 63)];
        b1.h4[0] = *(const f16x4*)&pwb[(m << 6) + ((32 + (quad << 3) + rot) & 63)];
        b1.h4[1] = *(const f16x4*)&pwb[(m << 6) + ((36 + (quad << 3) + rot) & 63)];

        // ---- O += P·V, both groups from the same V regs ----
#pragma unroll
        for (int dt = 0; dt < 4; ++dt) {
            oacca[dt] = MFMAH(a0.w, vr0[dt], oacca[dt]);
            oacca[dt] = MFMAH(a1.w, vr1[dt], oacca[dt]);
            oaccb[dt] = MFMAH(b0.w, vr0[dt], oaccb[dt]);
            oaccb[dt] = MFMAH(b1.w, vr1[dt], oaccb[dt]);
        }
    };

    // ---- main loop: 16 super-tiles of 128 keys, single-buffered ----
#pragma unroll 1
    for (int st = 0; st < SEQ / 128; ++st) {
        const size_t t0 = (size_t)st * 2;
        BAR();                       // all reads of previous super-tile done
        async16(khp + koff0 + (t0 << 12), &KH[wave << 9]);
        async16(khp + koff1 + (t0 << 12), &KH[(wave + 4) << 9]);
        async16(khp + koff0 + ((t0 + 1) << 12), &KH[4096 + (wave << 9)]);
        async16(khp + koff1 + ((t0 + 1) << 12), &KH[4096 + ((wave + 4) << 9)]);
        async16(vp + voff0 + (t0 << 6), &VF[wave << 9]);
        async16(vp + voff1 + (t0 << 6), &VF[(wave + 4) << 9]);
        async16(vp + voff0 + ((t0 + 1) << 6), &VF[4096 + (wave << 9)]);
        async16(vp + voff1 + ((t0 + 1) << 6), &VF[4096 + ((wave + 4) << 9)]);
        WAITVM(0);                   // my stages landed
        BAR();                       // everyone's stages landed
        tile(&KH[0], &VF[0]);
        tile(&KH[4096], &VF[4096]);
    }

    // ---- epilogue: per-group l reduce, normalize, fp16 store ----
#pragma unroll
    for (int g = 0; g < 2; ++g) {
        float lr = (g == 0) ? (la1 + la2) : (lb1 + lb2);
        lr += __shfl_xor(lr, 16);
        lr += __shfl_xor(lr, 32);
        float inv = 1.0f / lr;
        f32x4* oa = (g == 0) ? oacca : oaccb;
        size_t ob = ((size_t)(bi * SEQ + qt * 128 + g * 64 + wave * 16
                              + (quad << 2))) * DM + h * HD + m;
#pragma unroll
        for (int rg = 0; rg < 4; ++rg) {
            float il = __shfl(inv, (quad << 2) + rg, 16);
#pragma unroll
            for (int dt = 0; dt < 4; ++dt)
                oh[ob + (size_t)rg * DM + dt * 16] = (_Float16)(oa[dt][rg] * il);
        }
    }
}

// ---------------------------------------------------------------------------
// Kernel 3: out = attn @ Wo + bo, single-term fp16 MFMA + XCD row swizzle.
// ---------------------------------------------------------------------------
__global__ __launch_bounds__(256)
void out_mfma(const _Float16* __restrict__ ah,
              const _Float16* __restrict__ wth,
              const float* __restrict__ bias, float* __restrict__ out)
{
    __shared__ __align__(16) _Float16 SM[12288];
    _Float16* Ah = SM;
    _Float16* Bh = SM + 4096;

    const int tid  = threadIdx.x;
    const int lane = tid & 63;
    const int wave = tid >> 6;
    const int quad = lane >> 4;
    const int m    = lane & 15;
    const int wr   = wave >> 1, wc = wave & 1;

    // swizzle: XCD x owns row-blocks 8x..8x+7 (A slice 1MB + Wo-hi 0.5MB in L2)
    const int linear = blockIdx.x + (blockIdx.y << 6);   // 0..255
    const int xcd = linear & 7;
    const int r   = linear >> 3;                         // 0..31
    const int row0 = ((xcd << 3) + (r >> 2)) * 128;
    const int col0 = (r & 3) * 128;

    const size_t aoff0 = (size_t)(row0 + wave * 16 + m) * DM + (quad << 3);
    const size_t aoff1 = (size_t)(row0 + (wave + 4) * 16 + m) * DM + (quad << 3);
    const size_t boff0 = (size_t)(col0 + wave * 16 + m) * DM + (quad << 3);
    const size_t boff1 = (size_t)(col0 + (wave + 4) * 16 + m) * DM + (quad << 3);
    _Float16* lA0 = &Ah[wave << 9];     _Float16* lA1 = &Ah[(wave + 4) << 9];
    _Float16* lB0 = &Bh[wave << 9];     _Float16* lB1 = &Bh[(wave + 4) << 9];

    f32x4 acc[4][4];
#pragma unroll
    for (int i = 0; i < 4; ++i)
#pragma unroll
        for (int j = 0; j < 4; ++j) acc[i][j] = (f32x4){0.f, 0.f, 0.f, 0.f};

    for (int k0 = 0; k0 < DM; k0 += 32) {
        async16(ah + aoff0 + k0, lA0);
        async16(ah + aoff1 + k0, lA1);
        async16(wth + boff0 + k0, lB0);
        async16(wth + boff1 + k0, lB1);
        __syncthreads();

        f16x8 av[4], bvh[4];
#pragma unroll
        for (int t = 0; t < 4; ++t) {
            int ai  = ((((wr << 2) + t) << 6) + lane) << 3;
            int bi2 = ((((wc << 2) + t) << 6) + lane) << 3;
            av[t]  = *(const f16x8*)&Ah[ai];
            bvh[t] = *(const f16x8*)&Bh[bi2];
        }
#pragma unroll
        for (int rt = 0; rt < 4; ++rt)
#pragma unroll
            for (int ct = 0; ct < 4; ++ct)
                acc[rt][ct] = MFMAH(av[rt], bvh[ct], acc[rt][ct]);
        __syncthreads();
    }

    // epilogue: LDS transpose -> coalesced float4 stores
    const int row0w = row0 + wr * 64;
    const int colw  = col0 + wc * 64;
    float bc[4];
#pragma unroll
    for (int ct = 0; ct < 4; ++ct) bc[ct] = bias[colw + (ct << 4) + m];

    float* tb = (float*)SM + wave * 1088;
    const int rr = lane >> 2, jj = lane & 3;
#pragma unroll
    for (int rt = 0; rt < 4; ++rt) {
#pragma unroll
        for (int ct = 0; ct < 4; ++ct)
#pragma unroll
            for (int rg = 0; rg < 4; ++rg)
                tb[((quad << 2) + rg) * 68 + (ct << 4) + m] =
                    acc[rt][ct][rg] + bc[ct];
        LGKM0();
        int n = row0w + (rt << 4) + rr;
#pragma unroll
        for (int i = 0; i < 4; ++i) {
            int c = (jj << 2) + (i << 4);
            *(float4*)&out[(size_t)n * DM + colw + c] =
                *(const float4*)&tb[rr * 68 + c];
        }
    }
}

// ---------------------------------------------------------------------------
extern "C" void kernel_launch(void* const* d_in, const int* in_sizes, int n_in,
                              void* d_out, int out_size, void* d_ws, size_t ws_size,
                              hipStream_t stream)
{
    const float* x    = (const float*)d_in[0];
    const float* Wqkv = (const float*)d_in[1];
    const float* bqkv = (const float*)d_in[2];
    const float* Wo   = (const float*)d_in[3];
    const float* bo   = (const float*)d_in[4];
    float* out = (float*)d_out;

    char* ws = (char*)d_ws;
    const size_t MB = 1024 * 1024;
    _Float16* qh    = (_Float16*)(ws);                       // 8 MB [B,H,S,64]
    _Float16* oh    = (_Float16*)(ws + 8 * MB);              // 8 MB [B,S,512]
    _Float16* kh    = (_Float16*)(ws + 16 * MB);             // 8 MB [B,H,S,64]
    _Float16* vT    = (_Float16*)(ws + 24 * MB);             // 8 MB [B,H,64,S]
    _Float16* xh    = (_Float16*)(ws + 32 * MB);             // 8 MB [8192][512]
    _Float16* wqt_h = (_Float16*)(ws + 40 * MB);             // 1.5 MB [1536][512]
    _Float16* wot_h = (_Float16*)(ws + 42 * MB);             // 0.5 MB [512][512]
    float2*   rtab  = (float2*)(ws + 43 * MB);               // 0.5 MB [2048][32]

    prep_all<<<2560, 256, 0, stream>>>(x, Wqkv, Wo, rtab, wqt_h, wot_h, xh);
    qkv_mfma<<<dim3(64, 12), 256, 0, stream>>>(xh, wqt_h, bqkv, rtab,
                                               qh, kh, vT);
    attn_mfma<<<dim3(16, 32), 256, 0, stream>>>(qh, kh, vT, oh);
    out_mfma<<<dim3(64, 4), 256, 0, stream>>>(oh, wot_h, bo, out);
}

// Round 9
// 174.409 us; speedup vs baseline: 1.7106x; 1.0192x over previous
//
#include <hip/hip_runtime.h>
#include <math.h>

// Problem constants: B=4, S=2048, D=512, H=8, Hd=64
#define SEQ 2048
#define DM 512
#define NH 8
#define HD 64

typedef _Float16 f16x8 __attribute__((ext_vector_type(8)));
typedef _Float16 f16x4 __attribute__((ext_vector_type(4)));
typedef __fp16 h16x2 __attribute__((ext_vector_type(2)));   // builtin ABI type
typedef float f32x4 __attribute__((ext_vector_type(4)));
#define MFMAH(A, B, C) __builtin_amdgcn_mfma_f32_16x16x32_f16(A, B, C, 0, 0, 0)

__device__ __forceinline__ void async16(const void* g, void* l) {
    __builtin_amdgcn_global_load_lds((__attribute__((address_space(1))) void*)g,
                                     (__attribute__((address_space(3))) void*)l,
                                     16, 0, 0);
}
#define LGKM0() asm volatile("s_waitcnt lgkmcnt(0)" ::: "memory")
#define WAITVM(n) asm volatile("s_waitcnt vmcnt(" #n ")" ::: "memory")
#define SB0() __builtin_amdgcn_sched_barrier(0)
// raw barrier (no implicit vmcnt/lgkmcnt drain) fenced against code motion
#define BAR() do { SB0(); __builtin_amdgcn_s_barrier(); SB0(); } while (0)

// native exp2 (scores bounded |s|<=~9: no edge cases, 1-ulp HW accuracy fine)
#if __has_builtin(__builtin_amdgcn_exp2f)
#define EXP2(x) __builtin_amdgcn_exp2f(x)
#else
#define EXP2(x) exp2f(x)
#endif

// scale = 1/sqrt(64) * log2(e), folded into q at the QKV epilogue;
// scores land in the log2 domain -> exp2, no max subtraction needed.
#define QSCALE 0.18033688011112042f

// ---------------------------------------------------------------------------
// Fused prep kernel (range-dispatched by blockIdx.x). Single-term fp16 W
// (validated R8: absmax unchanged at 9.77e-4).
// ---------------------------------------------------------------------------
__global__ __launch_bounds__(256)
void prep_all(const float* __restrict__ x, const float* __restrict__ Wqkv,
              const float* __restrict__ Wo,
              float2* __restrict__ tab,
              _Float16* __restrict__ wqt_h, _Float16* __restrict__ wot_h,
              _Float16* __restrict__ xh)
{
    __shared__ float T[64][65];
    const int bid = blockIdx.x;
    const int tid = threadIdx.x;

    if (bid < 256) {
        int idx = bid * 256 + tid;   // 65536
        int s = idx >> 5, p = idx & 31;
        const float c = -0.28782313662425572f;  // -ln(10000)/32
        float f = (float)s * expf(c * (float)p);
        float sn, cs;
        sincosf(f, &sn, &cs);
        tab[idx] = make_float2(cs, sn);
        return;
    }
    if (bid < 512) {
        const float* W;
        _Float16 *hi;
        int N, bx, by;
        if (bid < 448) {
            int b = bid - 256;                 // 192 blocks: 24 x 8
            bx = b % 24; by = b / 24;
            W = Wqkv; hi = wqt_h; N = 3 * DM;
        } else {
            int b = bid - 448;                 // 64 blocks: 8 x 8
            bx = b % 8; by = b / 8;
            W = Wo; hi = wot_h; N = DM;
        }
        const int c0 = bx * 64, k0 = by * 64;
#pragma unroll
        for (int it = 0; it < 4; ++it) {
            int idx = it * 256 + tid;
            int r = idx >> 4, c4 = (idx & 15) << 2;
            *(float4*)&T[r][c4] = *(const float4*)&W[(size_t)(k0 + r) * N + c0 + c4];
        }
        __syncthreads();
#pragma unroll
        for (int it = 0; it < 4; ++it) {
            int idx = it * 256 + tid;
            int c = idx >> 4, k4 = (idx & 15) << 2;
            f16x4 hv;
#pragma unroll
            for (int r = 0; r < 4; ++r)
                hv[r] = (_Float16)T[k4 + r][c];
            *(f16x4*)&hi[(size_t)(c0 + c) * DM + k0 + k4] = hv;
        }
        return;
    }
    // x -> fp16 single
    size_t i = ((size_t)(bid - 512) * 256 + tid) << 3;
    float4 a0 = *(const float4*)&x[i];
    float4 a1 = *(const float4*)&x[i + 4];
    float fv[8] = {a0.x, a0.y, a0.z, a0.w, a1.x, a1.y, a1.z, a1.w};
    f16x8 hv;
#pragma unroll
    for (int j = 0; j < 8; ++j) hv[j] = (_Float16)fv[j];
    *(f16x8*)&xh[i] = hv;
}

// ---------------------------------------------------------------------------
// Kernel 1: QKV GEMM, single-term fp16 MFMA, XCD row swizzle (R8-validated).
// R9: double-buffered staging with counted vmcnt — stage K-step k+1 before
// computing k; WAITVM(4) leaves the next step's 4 loads in flight across
// the barriers (no per-step vmcnt(0) drain; at 3 blocks/CU TLP alone
// couldn't cover the ~600cy L2 drain). LDS 32 KB (2 bufs x (A 8K + B 8K)).
// ---------------------------------------------------------------------------
__global__ __launch_bounds__(256)
void qkv_mfma(const _Float16* __restrict__ xh,
              const _Float16* __restrict__ wth,
              const float* __restrict__ bias, const float2* __restrict__ tab,
              _Float16* __restrict__ qo, _Float16* __restrict__ ko,
              _Float16* __restrict__ vo)
{
    __shared__ __align__(16) _Float16 SM[16384];    // 32 KB: [buf][A|B]

    const int tid  = threadIdx.x;
    const int lane = tid & 63;
    const int wave = tid >> 6;
    const int quad = lane >> 4;
    const int m    = lane & 15;
    const int wr   = wave >> 1, wc = wave & 1;

    // swizzle: linear id -> (rowblk, by) with row-colocation per XCD
    const int linear = blockIdx.x + (blockIdx.y << 6);   // 0..767
    const int xcd = linear & 7;
    const int r   = linear >> 3;                         // 0..95
    const int row0 = ((xcd << 3) + r / 12) * 128;
    const int by   = r % 12;
    const int col0 = by * 128;

    const size_t aoff0 = (size_t)(row0 + wave * 16 + m) * DM + (quad << 3);
    const size_t aoff1 = (size_t)(row0 + (wave + 4) * 16 + m) * DM + (quad << 3);
    const size_t boff0 = (size_t)(col0 + wave * 16 + m) * DM + (quad << 3);
    const size_t boff1 = (size_t)(col0 + (wave + 4) * 16 + m) * DM + (quad << 3);

    f32x4 acc[4][4];
#pragma unroll
    for (int i = 0; i < 4; ++i)
#pragma unroll
        for (int j = 0; j < 4; ++j) acc[i][j] = (f32x4){0.f, 0.f, 0.f, 0.f};

#define QSTAGE(b, kk) do {                                                    \
        async16(xh + aoff0 + (kk), &SM[((b) << 13) + (wave << 9)]);           \
        async16(xh + aoff1 + (kk), &SM[((b) << 13) + ((wave + 4) << 9)]);     \
        async16(wth + boff0 + (kk), &SM[((b) << 13) + 4096 + (wave << 9)]);   \
        async16(wth + boff1 + (kk), &SM[((b) << 13) + 4096 + ((wave + 4) << 9)]); \
    } while (0)

    QSTAGE(0, 0);
#pragma unroll 1
    for (int k0 = 0; k0 < DM; k0 += 32) {
        const int b = (k0 >> 5) & 1;
        if (k0 + 32 < DM) { QSTAGE(b ^ 1, k0 + 32); WAITVM(4); }
        else              { WAITVM(0); }
        BAR();

        const _Float16* Ah = &SM[b << 13];
        const _Float16* Bh = Ah + 4096;
        f16x8 av[4], bvh[4];
#pragma unroll
        for (int t = 0; t < 4; ++t) {
            int ai  = ((((wr << 2) + t) << 6) + lane) << 3;
            int bi2 = ((((wc << 2) + t) << 6) + lane) << 3;
            av[t]  = *(const f16x8*)&Ah[ai];
            bvh[t] = *(const f16x8*)&Bh[bi2];
        }
#pragma unroll
        for (int rt = 0; rt < 4; ++rt)
#pragma unroll
            for (int ct = 0; ct < 4; ++ct)
                acc[rt][ct] = MFMAH(av[rt], bvh[ct], acc[rt][ct]);
        LGKM0();
        BAR();
    }
#undef QSTAGE

    // ---- epilogue ----
    const int sel   = by >> 2;              // 0=q 1=k 2=v
    const int head  = ((by << 1) + wc) & 7;
    const int row0w = row0 + wr * 64;
    const int bidx  = row0w >> 11;
    const int s0    = row0w & (SEQ - 1);
    const int colw  = col0 + wc * 64;

    float bc[4];
#pragma unroll
    for (int ct = 0; ct < 4; ++ct) bc[ct] = bias[colw + (ct << 4) + m];

    if (sel == 2) {
        // v: direct transposed store [B,H,d,s], f16x4 along s
#pragma unroll
        for (int ct = 0; ct < 4; ++ct) {
            int d = (ct << 4) + m;
#pragma unroll
            for (int rt = 0; rt < 4; ++rt) {
                f32x4 a = acc[rt][ct];
                f16x4 ov;
#pragma unroll
                for (int rg = 0; rg < 4; ++rg) ov[rg] = (_Float16)(a[rg] + bc[ct]);
                size_t off = ((size_t)((bidx * NH + head) * HD + d)) * SEQ
                           + s0 + (rt << 4) + (quad << 2);
                *(f16x4*)&vo[off] = ov;
            }
        }
    } else {
        // q/k: per-wave LDS transpose + RoPE + fp16 vector stores
        const float sc = (sel == 0) ? QSCALE : 1.0f;
        _Float16* dh = (sel == 0) ? qo : ko;
        float* tb = (float*)SM + wave * 1088;       // 16 x 68 f32 (17.4KB < 32KB)
        const int rr = lane >> 2, jj = lane & 3;
#pragma unroll
        for (int rt = 0; rt < 4; ++rt) {
#pragma unroll
            for (int ct = 0; ct < 4; ++ct)
#pragma unroll
                for (int rg = 0; rg < 4; ++rg)
                    tb[((quad << 2) + rg) * 68 + (ct << 4) + m] =
                        acc[rt][ct][rg] + bc[ct];
            LGKM0();
            int s = (row0w + (rt << 4) + rr) & (SEQ - 1);
#pragma unroll
            for (int i = 0; i < 4; ++i) {
                int c = (jj << 2) + (i << 4);
                float4 vv = *(const float4*)&tb[rr * 68 + c];
                float4 t4 = *(const float4*)&tab[(s << 5) + (c >> 1)];
                f16x4 hv;
                hv[0] = (_Float16)((vv.x * t4.x - vv.y * t4.y) * sc);
                hv[1] = (_Float16)((vv.x * t4.y + vv.y * t4.x) * sc);
                hv[2] = (_Float16)((vv.z * t4.z - vv.w * t4.w) * sc);
                hv[3] = (_Float16)((vv.z * t4.w + vv.w * t4.z) * sc);
                size_t off = (((size_t)(bidx * NH + head) * SEQ + s) << 6) + c;
                *(f16x4*)&dh[off] = hv;
            }
        }
    }
}

// ---------------------------------------------------------------------------
// Kernel 2: fp16 MFMA flash attention — 128 q/block, 32 q/wave (2 groups),
// R7/R8-validated compute body. R9: double-buffered SUPER-TILE staging with
// counted vmcnt — stage super-tile st+1 (8 async16) before computing st;
// WAITVM(8) keeps it in flight across both barriers (only the tail drains
// to 0). At 2 blocks/CU the old per-super-tile vmcnt(0)+BAR exposed the
// full L2 staging latency ~16x per block. LDS 80 KB (2x(16K K + 16K V)
// + 16K PW) = exactly 2 blocks/CU of the 160 KiB pool.
// ---------------------------------------------------------------------------
__global__ __launch_bounds__(256, 2)
void attn_mfma(const _Float16* __restrict__ qh_, const _Float16* __restrict__ kh_,
               const _Float16* __restrict__ vt, _Float16* __restrict__ oh)
{
    __shared__ __align__(16) _Float16 KH[2][8192];  // 2 bufs x super-tile (16 KB)
    __shared__ __align__(16) _Float16 VF[2][8192];
    __shared__ __align__(16) _Float16 PW[4][2048];  // per wave 2 x (16 x 64)

    const int tid  = threadIdx.x;
    const int lane = tid & 63;
    const int wave = tid >> 6;
    const int m    = lane & 15;
    const int quad = lane >> 4;

    // XCD-bijective swizzle: 512 blocks, xcd = linear&7 (round-robin);
    // bh = xcd + 8*(idx>>4): each XCD hosts 4 bh x 16 q-tiles.
    const int l   = blockIdx.x + (blockIdx.y << 4);
    const int idx = l >> 3;
    const int bh  = (l & 7) + ((idx >> 4) << 3);   // 0..31
    const int qt  = idx & 15;                      // 0..15 (128-q tiles)
    const int bi = bh >> 3, h = bh & 7;

    const _Float16* qhp = qh_ + ((size_t)bh * SEQ + qt * 128 + wave * 16) * HD;
    const _Float16* khp = kh_ + (size_t)bh * SEQ * HD;
    const _Float16* vp  = vt  + (size_t)bh * HD * SEQ;

    // Q B-frags, two groups 64 rows apart (pre-scaled by QSCALE)
    f16x8 qfa[2], qfb[2];
#pragma unroll
    for (int c = 0; c < 2; ++c) {
        qfa[c] = *(const f16x8*)&qhp[((size_t)m << 6) + c * 32 + (quad << 3)];
        qfb[c] = *(const f16x8*)&qhp[4096 + ((size_t)m << 6) + c * 32 + (quad << 3)];
    }

    f32x4 oacca[4], oaccb[4];   // [dt]: D[q=quad*4+rg][d=dt*16+m]
#pragma unroll
    for (int dt = 0; dt < 4; ++dt) {
        oacca[dt] = (f32x4){0.f, 0.f, 0.f, 0.f};
        oaccb[dt] = (f32x4){0.f, 0.f, 0.f, 0.f};
    }
    float la1 = 0.f, la2 = 0.f, lb1 = 0.f, lb2 = 0.f;

    // staging offsets: wave w stages K keys w*16+m and V rows d=w*16+m
    const size_t koff0 = ((size_t)(wave * 16 + m) << 6) + (quad << 3);
    const size_t koff1 = koff0 + 32;
    const size_t voff0 = ((size_t)(wave * 16 + m) << 11) + (quad << 3);
    const size_t voff1 = voff0 + 32;

    const h16x2 ones = {(__fp16)1.f, (__fp16)1.f};
    _Float16* pwa = PW[wave];
    _Float16* pwb = PW[wave] + 1024;
    const int rot = m << 2;          // per-row key rotation (multiple of 4)

    auto tile = [&](const _Float16* KB, const _Float16* VB) {
        // ---- S^T = K·Q^T for both q-groups; kf read ONCE per pair ----
        f32x4 sva[4], svb[4];
#pragma unroll
        for (int nt = 0; nt < 4; ++nt) {
            f32x4 sa = (f32x4){0.f, 0.f, 0.f, 0.f};
            f32x4 sb = (f32x4){0.f, 0.f, 0.f, 0.f};
#pragma unroll
            for (int c = 0; c < 2; ++c) {
                f16x8 kf = *(const f16x8*)&KB[((c * 4 + nt) * 64 + lane) << 3];
                sa = MFMAH(kf, qfa[c], sa);
                sb = MFMAH(kf, qfb[c], sb);
            }
            sva[nt] = sa;   // [key=nt*16+quad*4+rg][q=m], log2 domain
            svb[nt] = sb;
        }

        // ---- V to regs (read ONCE, feeds both groups' PV) ----
        f16x8 vr0[4], vr1[4];
#pragma unroll
        for (int dt = 0; dt < 4; ++dt) {
            vr0[dt] = *(const f16x8*)&VB[((0 * 4 + dt) * 64 + lane) << 3];
            vr1[dt] = *(const f16x8*)&VB[((1 * 4 + dt) * 64 + lane) << 3];
        }

        // ---- softmax + pack + rotated PW write, both groups ----
#pragma unroll
        for (int nt = 0; nt < 4; ++nt) {
            union { unsigned int u[2]; f16x4 v; } pka, pkb;
#pragma unroll
            for (int i = 0; i < 2; ++i) {
                h16x2 ta = __builtin_amdgcn_cvt_pkrtz(EXP2(sva[nt][2 * i]),
                                                      EXP2(sva[nt][2 * i + 1]));
                h16x2 tb = __builtin_amdgcn_cvt_pkrtz(EXP2(svb[nt][2 * i]),
                                                      EXP2(svb[nt][2 * i + 1]));
                if (i == 0) { la1 = __builtin_amdgcn_fdot2(ta, ones, la1, false);
                              lb1 = __builtin_amdgcn_fdot2(tb, ones, lb1, false); }
                else        { la2 = __builtin_amdgcn_fdot2(ta, ones, la2, false);
                              lb2 = __builtin_amdgcn_fdot2(tb, ones, lb2, false); }
                union { h16x2 hh; unsigned int uu; } ca, cb;
                ca.hh = ta; cb.hh = tb;
                pka.u[i] = ca.uu; pkb.u[i] = cb.uu;
            }
            int pos = ((nt << 4) + (quad << 2) + rot) & 63;
            *(f16x4*)&pwa[(m << 6) + pos] = pka.v;
            *(f16x4*)&pwb[(m << 6) + pos] = pkb.v;
        }
        LGKM0();
        union { f16x4 h4[2]; f16x8 w; } a0, a1, b0, b1;
        a0.h4[0] = *(const f16x4*)&pwa[(m << 6) + (((quad << 3) + rot) & 63)];
        a0.h4[1] = *(const f16x4*)&pwa[(m << 6) + (((quad << 3) + 4 + rot) & 63)];
        a1.h4[0] = *(const f16x4*)&pwa[(m << 6) + ((32 + (quad << 3) + rot) & 63)];
        a1.h4[1] = *(const f16x4*)&pwa[(m << 6) + ((36 + (quad << 3) + rot) & 63)];
        b0.h4[0] = *(const f16x4*)&pwb[(m << 6) + (((quad << 3) + rot) & 63)];
        b0.h4[1] = *(const f16x4*)&pwb[(m << 6) + (((quad << 3) + 4 + rot) & 63)];
        b1.h4[0] = *(const f16x4*)&pwb[(m << 6) + ((32 + (quad << 3) + rot) & 63)];
        b1.h4[1] = *(const f16x4*)&pwb[(m << 6) + ((36 + (quad << 3) + rot) & 63)];

        // ---- O += P·V, both groups from the same V regs ----
#pragma unroll
        for (int dt = 0; dt < 4; ++dt) {
            oacca[dt] = MFMAH(a0.w, vr0[dt], oacca[dt]);
            oacca[dt] = MFMAH(a1.w, vr1[dt], oacca[dt]);
            oaccb[dt] = MFMAH(b0.w, vr0[dt], oaccb[dt]);
            oaccb[dt] = MFMAH(b1.w, vr1[dt], oaccb[dt]);
        }
    };

#define STAGE(b, st_) do { const size_t t0 = (size_t)(st_) * 2;               \
        async16(khp + koff0 + (t0 << 12), &KH[b][wave << 9]);                 \
        async16(khp + koff1 + (t0 << 12), &KH[b][(wave + 4) << 9]);           \
        async16(khp + koff0 + ((t0 + 1) << 12), &KH[b][4096 + (wave << 9)]);  \
        async16(khp + koff1 + ((t0 + 1) << 12), &KH[b][4096 + ((wave + 4) << 9)]); \
        async16(vp + voff0 + (t0 << 6), &VF[b][wave << 9]);                   \
        async16(vp + voff1 + (t0 << 6), &VF[b][(wave + 4) << 9]);             \
        async16(vp + voff0 + ((t0 + 1) << 6), &VF[b][4096 + (wave << 9)]);    \
        async16(vp + voff1 + ((t0 + 1) << 6), &VF[b][4096 + ((wave + 4) << 9)]); \
    } while (0)

    // ---- main loop: 16 super-tiles, double-buffered, counted vmcnt ----
    STAGE(0, 0);
#pragma unroll 1
    for (int st = 0; st < SEQ / 128; ++st) {
        const int b = st & 1;
        if (st + 1 < SEQ / 128) { STAGE(b ^ 1, st + 1); WAITVM(8); }
        else                    { WAITVM(0); }
        BAR();                       // super-tile st landed for all waves
        tile(&KH[b][0], &VF[b][0]);
        tile(&KH[b][4096], &VF[b][4096]);
        LGKM0();                     // my ds reads of buf b retired
        BAR();                       // everyone done -> b restageable
    }
#undef STAGE

    // ---- epilogue: per-group l reduce, normalize, fp16 store ----
#pragma unroll
    for (int g = 0; g < 2; ++g) {
        float lr = (g == 0) ? (la1 + la2) : (lb1 + lb2);
        lr += __shfl_xor(lr, 16);
        lr += __shfl_xor(lr, 32);
        float inv = 1.0f / lr;
        f32x4* oa = (g == 0) ? oacca : oaccb;
        size_t ob = ((size_t)(bi * SEQ + qt * 128 + g * 64 + wave * 16
                              + (quad << 2))) * DM + h * HD + m;
#pragma unroll
        for (int rg = 0; rg < 4; ++rg) {
            float il = __shfl(inv, (quad << 2) + rg, 16);
#pragma unroll
            for (int dt = 0; dt < 4; ++dt)
                oh[ob + (size_t)rg * DM + dt * 16] = (_Float16)(oa[dt][rg] * il);
        }
    }
}

// ---------------------------------------------------------------------------
// Kernel 3: out = attn @ Wo + bo, single-term fp16 MFMA + XCD row swizzle.
// (unchanged from R8 — small; kept for attribution clarity)
// ---------------------------------------------------------------------------
__global__ __launch_bounds__(256)
void out_mfma(const _Float16* __restrict__ ah,
              const _Float16* __restrict__ wth,
              const float* __restrict__ bias, float* __restrict__ out)
{
    __shared__ __align__(16) _Float16 SM[12288];
    _Float16* Ah = SM;
    _Float16* Bh = SM + 4096;

    const int tid  = threadIdx.x;
    const int lane = tid & 63;
    const int wave = tid >> 6;
    const int quad = lane >> 4;
    const int m    = lane & 15;
    const int wr   = wave >> 1, wc = wave & 1;

    // swizzle: XCD x owns row-blocks 8x..8x+7 (A slice 1MB + Wo-hi 0.5MB in L2)
    const int linear = blockIdx.x + (blockIdx.y << 6);   // 0..255
    const int xcd = linear & 7;
    const int r   = linear >> 3;                         // 0..31
    const int row0 = ((xcd << 3) + (r >> 2)) * 128;
    const int col0 = (r & 3) * 128;

    const size_t aoff0 = (size_t)(row0 + wave * 16 + m) * DM + (quad << 3);
    const size_t aoff1 = (size_t)(row0 + (wave + 4) * 16 + m) * DM + (quad << 3);
    const size_t boff0 = (size_t)(col0 + wave * 16 + m) * DM + (quad << 3);
    const size_t boff1 = (size_t)(col0 + (wave + 4) * 16 + m) * DM + (quad << 3);
    _Float16* lA0 = &Ah[wave << 9];     _Float16* lA1 = &Ah[(wave + 4) << 9];
    _Float16* lB0 = &Bh[wave << 9];     _Float16* lB1 = &Bh[(wave + 4) << 9];

    f32x4 acc[4][4];
#pragma unroll
    for (int i = 0; i < 4; ++i)
#pragma unroll
        for (int j = 0; j < 4; ++j) acc[i][j] = (f32x4){0.f, 0.f, 0.f, 0.f};

    for (int k0 = 0; k0 < DM; k0 += 32) {
        async16(ah + aoff0 + k0, lA0);
        async16(ah + aoff1 + k0, lA1);
        async16(wth + boff0 + k0, lB0);
        async16(wth + boff1 + k0, lB1);
        __syncthreads();

        f16x8 av[4], bvh[4];
#pragma unroll
        for (int t = 0; t < 4; ++t) {
            int ai  = ((((wr << 2) + t) << 6) + lane) << 3;
            int bi2 = ((((wc << 2) + t) << 6) + lane) << 3;
            av[t]  = *(const f16x8*)&Ah[ai];
            bvh[t] = *(const f16x8*)&Bh[bi2];
        }
#pragma unroll
        for (int rt = 0; rt < 4; ++rt)
#pragma unroll
            for (int ct = 0; ct < 4; ++ct)
                acc[rt][ct] = MFMAH(av[rt], bvh[ct], acc[rt][ct]);
        __syncthreads();
    }

    // epilogue: LDS transpose -> coalesced float4 stores
    const int row0w = row0 + wr * 64;
    const int colw  = col0 + wc * 64;
    float bc[4];
#pragma unroll
    for (int ct = 0; ct < 4; ++ct) bc[ct] = bias[colw + (ct << 4) + m];

    float* tb = (float*)SM + wave * 1088;
    const int rr = lane >> 2, jj = lane & 3;
#pragma unroll
    for (int rt = 0; rt < 4; ++rt) {
#pragma unroll
        for (int ct = 0; ct < 4; ++ct)
#pragma unroll
            for (int rg = 0; rg < 4; ++rg)
                tb[((quad << 2) + rg) * 68 + (ct << 4) + m] =
                    acc[rt][ct][rg] + bc[ct];
        LGKM0();
        int n = row0w + (rt << 4) + rr;
#pragma unroll
        for (int i = 0; i < 4; ++i) {
            int c = (jj << 2) + (i << 4);
            *(float4*)&out[(size_t)n * DM + colw + c] =
                *(const float4*)&tb[rr * 68 + c];
        }
    }
}

// ---------------------------------------------------------------------------
extern "C" void kernel_launch(void* const* d_in, const int* in_sizes, int n_in,
                              void* d_out, int out_size, void* d_ws, size_t ws_size,
                              hipStream_t stream)
{
    const float* x    = (const float*)d_in[0];
    const float* Wqkv = (const float*)d_in[1];
    const float* bqkv = (const float*)d_in[2];
    const float* Wo   = (const float*)d_in[3];
    const float* bo   = (const float*)d_in[4];
    float* out = (float*)d_out;

    char* ws = (char*)d_ws;
    const size_t MB = 1024 * 1024;
    _Float16* qh    = (_Float16*)(ws);                       // 8 MB [B,H,S,64]
    _Float16* oh    = (_Float16*)(ws + 8 * MB);              // 8 MB [B,S,512]
    _Float16* kh    = (_Float16*)(ws + 16 * MB);             // 8 MB [B,H,S,64]
    _Float16* vT    = (_Float16*)(ws + 24 * MB);             // 8 MB [B,H,64,S]
    _Float16* xh    = (_Float16*)(ws + 32 * MB);             // 8 MB [8192][512]
    _Float16* wqt_h = (_Float16*)(ws + 40 * MB);             // 1.5 MB [1536][512]
    _Float16* wot_h = (_Float16*)(ws + 42 * MB);             // 0.5 MB [512][512]
    float2*   rtab  = (float2*)(ws + 43 * MB);               // 0.5 MB [2048][32]

    prep_all<<<2560, 256, 0, stream>>>(x, Wqkv, Wo, rtab, wqt_h, wot_h, xh);
    qkv_mfma<<<dim3(64, 12), 256, 0, stream>>>(xh, wqt_h, bqkv, rtab,
                                               qh, kh, vT);
    attn_mfma<<<dim3(16, 32), 256, 0, stream>>>(qh, kh, vT, oh);
    out_mfma<<<dim3(64, 4), 256, 0, stream>>>(oh, wot_h, bo, out);
}

// Round 10
// 168.146 us; speedup vs baseline: 1.7743x; 1.0372x over previous
//
#include <hip/hip_runtime.h>
#include <math.h>

// Problem constants: B=4, S=2048, D=512, H=8, Hd=64
#define SEQ 2048
#define DM 512
#define NH 8
#define HD 64

typedef _Float16 f16x8 __attribute__((ext_vector_type(8)));
typedef _Float16 f16x4 __attribute__((ext_vector_type(4)));
typedef __fp16 h16x2 __attribute__((ext_vector_type(2)));   // builtin ABI type
typedef float f32x4 __attribute__((ext_vector_type(4)));
#define MFMAH(A, B, C) __builtin_amdgcn_mfma_f32_16x16x32_f16(A, B, C, 0, 0, 0)

__device__ __forceinline__ void async16(const void* g, void* l) {
    __builtin_amdgcn_global_load_lds((__attribute__((address_space(1))) void*)g,
                                     (__attribute__((address_space(3))) void*)l,
                                     16, 0, 0);
}
#define LGKM0() asm volatile("s_waitcnt lgkmcnt(0)" ::: "memory")
#define WAITVM(n) asm volatile("s_waitcnt vmcnt(" #n ")" ::: "memory")
#define SB0() __builtin_amdgcn_sched_barrier(0)
// raw barrier (no implicit vmcnt/lgkmcnt drain) fenced against code motion
#define BAR() do { SB0(); __builtin_amdgcn_s_barrier(); SB0(); } while (0)

// native exp2 (scores bounded |s|<=~9: no edge cases, 1-ulp HW accuracy fine)
#if __has_builtin(__builtin_amdgcn_exp2f)
#define EXP2(x) __builtin_amdgcn_exp2f(x)
#else
#define EXP2(x) exp2f(x)
#endif

// scale = 1/sqrt(64) * log2(e), folded into q at the QKV epilogue;
// scores land in the log2 domain -> exp2, no max subtraction needed.
#define QSCALE 0.18033688011112042f

// ---------------------------------------------------------------------------
// Fused prep kernel (range-dispatched by blockIdx.x). Single-term fp16 W
// (validated R8: absmax unchanged at 9.77e-4).
// ---------------------------------------------------------------------------
__global__ __launch_bounds__(256)
void prep_all(const float* __restrict__ x, const float* __restrict__ Wqkv,
              const float* __restrict__ Wo,
              float2* __restrict__ tab,
              _Float16* __restrict__ wqt_h, _Float16* __restrict__ wot_h,
              _Float16* __restrict__ xh)
{
    __shared__ float T[64][65];
    const int bid = blockIdx.x;
    const int tid = threadIdx.x;

    if (bid < 256) {
        int idx = bid * 256 + tid;   // 65536
        int s = idx >> 5, p = idx & 31;
        const float c = -0.28782313662425572f;  // -ln(10000)/32
        float f = (float)s * expf(c * (float)p);
        float sn, cs;
        sincosf(f, &sn, &cs);
        tab[idx] = make_float2(cs, sn);
        return;
    }
    if (bid < 512) {
        const float* W;
        _Float16 *hi;
        int N, bx, by;
        if (bid < 448) {
            int b = bid - 256;                 // 192 blocks: 24 x 8
            bx = b % 24; by = b / 24;
            W = Wqkv; hi = wqt_h; N = 3 * DM;
        } else {
            int b = bid - 448;                 // 64 blocks: 8 x 8
            bx = b % 8; by = b / 8;
            W = Wo; hi = wot_h; N = DM;
        }
        const int c0 = bx * 64, k0 = by * 64;
#pragma unroll
        for (int it = 0; it < 4; ++it) {
            int idx = it * 256 + tid;
            int r = idx >> 4, c4 = (idx & 15) << 2;
            *(float4*)&T[r][c4] = *(const float4*)&W[(size_t)(k0 + r) * N + c0 + c4];
        }
        __syncthreads();
#pragma unroll
        for (int it = 0; it < 4; ++it) {
            int idx = it * 256 + tid;
            int c = idx >> 4, k4 = (idx & 15) << 2;
            f16x4 hv;
#pragma unroll
            for (int r = 0; r < 4; ++r)
                hv[r] = (_Float16)T[k4 + r][c];
            *(f16x4*)&hi[(size_t)(c0 + c) * DM + k0 + k4] = hv;
        }
        return;
    }
    // x -> fp16 single
    size_t i = ((size_t)(bid - 512) * 256 + tid) << 3;
    float4 a0 = *(const float4*)&x[i];
    float4 a1 = *(const float4*)&x[i + 4];
    float fv[8] = {a0.x, a0.y, a0.z, a0.w, a1.x, a1.y, a1.z, a1.w};
    f16x8 hv;
#pragma unroll
    for (int j = 0; j < 8; ++j) hv[j] = (_Float16)fv[j];
    *(f16x8*)&xh[i] = hv;
}

// ---------------------------------------------------------------------------
// Kernel 1: QKV GEMM, single-term fp16 MFMA, XCD row swizzle + dbuf counted
// vmcnt (R8/R9-validated). LDS 32 KB (2 bufs x (A 8K + B 8K)).
// ---------------------------------------------------------------------------
__global__ __launch_bounds__(256)
void qkv_mfma(const _Float16* __restrict__ xh,
              const _Float16* __restrict__ wth,
              const float* __restrict__ bias, const float2* __restrict__ tab,
              _Float16* __restrict__ qo, _Float16* __restrict__ ko,
              _Float16* __restrict__ vo)
{
    __shared__ __align__(16) _Float16 SM[16384];    // 32 KB: [buf][A|B]

    const int tid  = threadIdx.x;
    const int lane = tid & 63;
    const int wave = tid >> 6;
    const int quad = lane >> 4;
    const int m    = lane & 15;
    const int wr   = wave >> 1, wc = wave & 1;

    // swizzle: linear id -> (rowblk, by) with row-colocation per XCD
    const int linear = blockIdx.x + (blockIdx.y << 6);   // 0..767
    const int xcd = linear & 7;
    const int r   = linear >> 3;                         // 0..95
    const int row0 = ((xcd << 3) + r / 12) * 128;
    const int by   = r % 12;
    const int col0 = by * 128;

    const size_t aoff0 = (size_t)(row0 + wave * 16 + m) * DM + (quad << 3);
    const size_t aoff1 = (size_t)(row0 + (wave + 4) * 16 + m) * DM + (quad << 3);
    const size_t boff0 = (size_t)(col0 + wave * 16 + m) * DM + (quad << 3);
    const size_t boff1 = (size_t)(col0 + (wave + 4) * 16 + m) * DM + (quad << 3);

    f32x4 acc[4][4];
#pragma unroll
    for (int i = 0; i < 4; ++i)
#pragma unroll
        for (int j = 0; j < 4; ++j) acc[i][j] = (f32x4){0.f, 0.f, 0.f, 0.f};

#define QSTAGE(b, kk) do {                                                    \
        async16(xh + aoff0 + (kk), &SM[((b) << 13) + (wave << 9)]);           \
        async16(xh + aoff1 + (kk), &SM[((b) << 13) + ((wave + 4) << 9)]);     \
        async16(wth + boff0 + (kk), &SM[((b) << 13) + 4096 + (wave << 9)]);   \
        async16(wth + boff1 + (kk), &SM[((b) << 13) + 4096 + ((wave + 4) << 9)]); \
    } while (0)

    QSTAGE(0, 0);
#pragma unroll 1
    for (int k0 = 0; k0 < DM; k0 += 32) {
        const int b = (k0 >> 5) & 1;
        if (k0 + 32 < DM) { QSTAGE(b ^ 1, k0 + 32); WAITVM(4); }
        else              { WAITVM(0); }
        BAR();

        const _Float16* Ah = &SM[b << 13];
        const _Float16* Bh = Ah + 4096;
        f16x8 av[4], bvh[4];
#pragma unroll
        for (int t = 0; t < 4; ++t) {
            int ai  = ((((wr << 2) + t) << 6) + lane) << 3;
            int bi2 = ((((wc << 2) + t) << 6) + lane) << 3;
            av[t]  = *(const f16x8*)&Ah[ai];
            bvh[t] = *(const f16x8*)&Bh[bi2];
        }
#pragma unroll
        for (int rt = 0; rt < 4; ++rt)
#pragma unroll
            for (int ct = 0; ct < 4; ++ct)
                acc[rt][ct] = MFMAH(av[rt], bvh[ct], acc[rt][ct]);
        LGKM0();
        BAR();
    }
#undef QSTAGE

    // ---- epilogue ----
    const int sel   = by >> 2;              // 0=q 1=k 2=v
    const int head  = ((by << 1) + wc) & 7;
    const int row0w = row0 + wr * 64;
    const int bidx  = row0w >> 11;
    const int s0    = row0w & (SEQ - 1);
    const int colw  = col0 + wc * 64;

    float bc[4];
#pragma unroll
    for (int ct = 0; ct < 4; ++ct) bc[ct] = bias[colw + (ct << 4) + m];

    if (sel == 2) {
        // v: direct transposed store [B,H,d,s], f16x4 along s
#pragma unroll
        for (int ct = 0; ct < 4; ++ct) {
            int d = (ct << 4) + m;
#pragma unroll
            for (int rt = 0; rt < 4; ++rt) {
                f32x4 a = acc[rt][ct];
                f16x4 ov;
#pragma unroll
                for (int rg = 0; rg < 4; ++rg) ov[rg] = (_Float16)(a[rg] + bc[ct]);
                size_t off = ((size_t)((bidx * NH + head) * HD + d)) * SEQ
                           + s0 + (rt << 4) + (quad << 2);
                *(f16x4*)&vo[off] = ov;
            }
        }
    } else {
        // q/k: per-wave LDS transpose + RoPE + fp16 vector stores
        const float sc = (sel == 0) ? QSCALE : 1.0f;
        _Float16* dh = (sel == 0) ? qo : ko;
        float* tb = (float*)SM + wave * 1088;       // 16 x 68 f32 (17.4KB < 32KB)
        const int rr = lane >> 2, jj = lane & 3;
#pragma unroll
        for (int rt = 0; rt < 4; ++rt) {
#pragma unroll
            for (int ct = 0; ct < 4; ++ct)
#pragma unroll
                for (int rg = 0; rg < 4; ++rg)
                    tb[((quad << 2) + rg) * 68 + (ct << 4) + m] =
                        acc[rt][ct][rg] + bc[ct];
            LGKM0();
            int s = (row0w + (rt << 4) + rr) & (SEQ - 1);
#pragma unroll
            for (int i = 0; i < 4; ++i) {
                int c = (jj << 2) + (i << 4);
                float4 vv = *(const float4*)&tb[rr * 68 + c];
                float4 t4 = *(const float4*)&tab[(s << 5) + (c >> 1)];
                f16x4 hv;
                hv[0] = (_Float16)((vv.x * t4.x - vv.y * t4.y) * sc);
                hv[1] = (_Float16)((vv.x * t4.y + vv.y * t4.x) * sc);
                hv[2] = (_Float16)((vv.z * t4.z - vv.w * t4.w) * sc);
                hv[3] = (_Float16)((vv.z * t4.w + vv.w * t4.z) * sc);
                size_t off = (((size_t)(bidx * NH + head) * SEQ + s) << 6) + c;
                *(f16x4*)&dh[off] = hv;
            }
        }
    }
}

// ---------------------------------------------------------------------------
// Kernel 2: fp16 MFMA flash attention — 128 q/block, 32 q/wave (2 groups),
// R7-validated body + R9 dbuf. R10: PW rotation granularity 4 -> 8
// (rot = 8*(m&7)): every 8-key A-frag run stays contiguous and 16B-aligned,
// so each pf load is ONE ds_read_b128 (was 4 ds_read_b64): PW reads
// 16 b64 -> 4 b128 per tile per wave (-48 LDS-issue cyc of the ~336/tile
// that the R9 post-mortem identified as the floor). Same bijection
// pos=(key+rot)&63 on write and read; 4-runs and 8-runs never cross the
// &63 wrap (starts are multiples of 4 resp. 8).
// ---------------------------------------------------------------------------
__global__ __launch_bounds__(256, 2)
void attn_mfma(const _Float16* __restrict__ qh_, const _Float16* __restrict__ kh_,
               const _Float16* __restrict__ vt, _Float16* __restrict__ oh)
{
    __shared__ __align__(16) _Float16 KH[2][8192];  // 2 bufs x super-tile (16 KB)
    __shared__ __align__(16) _Float16 VF[2][8192];
    __shared__ __align__(16) _Float16 PW[4][2048];  // per wave 2 x (16 x 64)

    const int tid  = threadIdx.x;
    const int lane = tid & 63;
    const int wave = tid >> 6;
    const int m    = lane & 15;
    const int quad = lane >> 4;

    // XCD-bijective swizzle: 512 blocks, xcd = linear&7 (round-robin);
    // bh = xcd + 8*(idx>>4): each XCD hosts 4 bh x 16 q-tiles.
    const int l   = blockIdx.x + (blockIdx.y << 4);
    const int idx = l >> 3;
    const int bh  = (l & 7) + ((idx >> 4) << 3);   // 0..31
    const int qt  = idx & 15;                      // 0..15 (128-q tiles)
    const int bi = bh >> 3, h = bh & 7;

    const _Float16* qhp = qh_ + ((size_t)bh * SEQ + qt * 128 + wave * 16) * HD;
    const _Float16* khp = kh_ + (size_t)bh * SEQ * HD;
    const _Float16* vp  = vt  + (size_t)bh * HD * SEQ;

    // Q B-frags, two groups 64 rows apart (pre-scaled by QSCALE)
    f16x8 qfa[2], qfb[2];
#pragma unroll
    for (int c = 0; c < 2; ++c) {
        qfa[c] = *(const f16x8*)&qhp[((size_t)m << 6) + c * 32 + (quad << 3)];
        qfb[c] = *(const f16x8*)&qhp[4096 + ((size_t)m << 6) + c * 32 + (quad << 3)];
    }

    f32x4 oacca[4], oaccb[4];   // [dt]: D[q=quad*4+rg][d=dt*16+m]
#pragma unroll
    for (int dt = 0; dt < 4; ++dt) {
        oacca[dt] = (f32x4){0.f, 0.f, 0.f, 0.f};
        oaccb[dt] = (f32x4){0.f, 0.f, 0.f, 0.f};
    }
    float la1 = 0.f, la2 = 0.f, lb1 = 0.f, lb2 = 0.f;

    // staging offsets: wave w stages K keys w*16+m and V rows d=w*16+m
    const size_t koff0 = ((size_t)(wave * 16 + m) << 6) + (quad << 3);
    const size_t koff1 = koff0 + 32;
    const size_t voff0 = ((size_t)(wave * 16 + m) << 11) + (quad << 3);
    const size_t voff1 = voff0 + 32;

    const h16x2 ones = {(__fp16)1.f, (__fp16)1.f};
    _Float16* pwa = PW[wave];
    _Float16* pwb = PW[wave] + 1024;
    const int rot = (m & 7) << 3;    // per-row key rotation, granularity 8

    auto tile = [&](const _Float16* KB, const _Float16* VB) {
        // ---- S^T = K·Q^T for both q-groups; kf read ONCE per pair ----
        f32x4 sva[4], svb[4];
#pragma unroll
        for (int nt = 0; nt < 4; ++nt) {
            f32x4 sa = (f32x4){0.f, 0.f, 0.f, 0.f};
            f32x4 sb = (f32x4){0.f, 0.f, 0.f, 0.f};
#pragma unroll
            for (int c = 0; c < 2; ++c) {
                f16x8 kf = *(const f16x8*)&KB[((c * 4 + nt) * 64 + lane) << 3];
                sa = MFMAH(kf, qfa[c], sa);
                sb = MFMAH(kf, qfb[c], sb);
            }
            sva[nt] = sa;   // [key=nt*16+quad*4+rg][q=m], log2 domain
            svb[nt] = sb;
        }

        // ---- V to regs (read ONCE, feeds both groups' PV) ----
        f16x8 vr0[4], vr1[4];
#pragma unroll
        for (int dt = 0; dt < 4; ++dt) {
            vr0[dt] = *(const f16x8*)&VB[((0 * 4 + dt) * 64 + lane) << 3];
            vr1[dt] = *(const f16x8*)&VB[((1 * 4 + dt) * 64 + lane) << 3];
        }

        // ---- softmax + pack + rotated PW write, both groups ----
#pragma unroll
        for (int nt = 0; nt < 4; ++nt) {
            union { unsigned int u[2]; f16x4 v; } pka, pkb;
#pragma unroll
            for (int i = 0; i < 2; ++i) {
                h16x2 ta = __builtin_amdgcn_cvt_pkrtz(EXP2(sva[nt][2 * i]),
                                                      EXP2(sva[nt][2 * i + 1]));
                h16x2 tb = __builtin_amdgcn_cvt_pkrtz(EXP2(svb[nt][2 * i]),
                                                      EXP2(svb[nt][2 * i + 1]));
                if (i == 0) { la1 = __builtin_amdgcn_fdot2(ta, ones, la1, false);
                              lb1 = __builtin_amdgcn_fdot2(tb, ones, lb1, false); }
                else        { la2 = __builtin_amdgcn_fdot2(ta, ones, la2, false);
                              lb2 = __builtin_amdgcn_fdot2(tb, ones, lb2, false); }
                union { h16x2 hh; unsigned int uu; } ca, cb;
                ca.hh = ta; cb.hh = tb;
                pka.u[i] = ca.uu; pkb.u[i] = cb.uu;
            }
            int pos = ((nt << 4) + (quad << 2) + rot) & 63;
            *(f16x4*)&pwa[(m << 6) + pos] = pka.v;
            *(f16x4*)&pwb[(m << 6) + pos] = pkb.v;
        }
        LGKM0();
        // ---- A-frags: single b128 each (8-aligned contiguous runs) ----
        f16x8 pf0a = *(const f16x8*)&pwa[(m << 6) + (((quad << 3) + rot) & 63)];
        f16x8 pf1a = *(const f16x8*)&pwa[(m << 6) + ((32 + (quad << 3) + rot) & 63)];
        f16x8 pf0b = *(const f16x8*)&pwb[(m << 6) + (((quad << 3) + rot) & 63)];
        f16x8 pf1b = *(const f16x8*)&pwb[(m << 6) + ((32 + (quad << 3) + rot) & 63)];

        // ---- O += P·V, both groups from the same V regs ----
#pragma unroll
        for (int dt = 0; dt < 4; ++dt) {
            oacca[dt] = MFMAH(pf0a, vr0[dt], oacca[dt]);
            oacca[dt] = MFMAH(pf1a, vr1[dt], oacca[dt]);
            oaccb[dt] = MFMAH(pf0b, vr0[dt], oaccb[dt]);
            oaccb[dt] = MFMAH(pf1b, vr1[dt], oaccb[dt]);
        }
    };

#define STAGE(b, st_) do { const size_t t0 = (size_t)(st_) * 2;               \
        async16(khp + koff0 + (t0 << 12), &KH[b][wave << 9]);                 \
        async16(khp + koff1 + (t0 << 12), &KH[b][(wave + 4) << 9]);           \
        async16(khp + koff0 + ((t0 + 1) << 12), &KH[b][4096 + (wave << 9)]);  \
        async16(khp + koff1 + ((t0 + 1) << 12), &KH[b][4096 + ((wave + 4) << 9)]); \
        async16(vp + voff0 + (t0 << 6), &VF[b][wave << 9]);                   \
        async16(vp + voff1 + (t0 << 6), &VF[b][(wave + 4) << 9]);             \
        async16(vp + voff0 + ((t0 + 1) << 6), &VF[b][4096 + (wave << 9)]);    \
        async16(vp + voff1 + ((t0 + 1) << 6), &VF[b][4096 + ((wave + 4) << 9)]); \
    } while (0)

    // ---- main loop: 16 super-tiles, double-buffered, counted vmcnt ----
    STAGE(0, 0);
#pragma unroll 1
    for (int st = 0; st < SEQ / 128; ++st) {
        const int b = st & 1;
        if (st + 1 < SEQ / 128) { STAGE(b ^ 1, st + 1); WAITVM(8); }
        else                    { WAITVM(0); }
        BAR();                       // super-tile st landed for all waves
        tile(&KH[b][0], &VF[b][0]);
        tile(&KH[b][4096], &VF[b][4096]);
        LGKM0();                     // my ds reads of buf b retired
        BAR();                       // everyone done -> b restageable
    }
#undef STAGE

    // ---- epilogue: per-group l reduce, normalize, fp16 store ----
#pragma unroll
    for (int g = 0; g < 2; ++g) {
        float lr = (g == 0) ? (la1 + la2) : (lb1 + lb2);
        lr += __shfl_xor(lr, 16);
        lr += __shfl_xor(lr, 32);
        float inv = 1.0f / lr;
        f32x4* oa = (g == 0) ? oacca : oaccb;
        size_t ob = ((size_t)(bi * SEQ + qt * 128 + g * 64 + wave * 16
                              + (quad << 2))) * DM + h * HD + m;
#pragma unroll
        for (int rg = 0; rg < 4; ++rg) {
            float il = __shfl(inv, (quad << 2) + rg, 16);
#pragma unroll
            for (int dt = 0; dt < 4; ++dt)
                oh[ob + (size_t)rg * DM + dt * 16] = (_Float16)(oa[dt][rg] * il);
        }
    }
}

// ---------------------------------------------------------------------------
// Kernel 3: out = attn @ Wo + bo, single-term fp16 MFMA + XCD row swizzle.
// R10: dbuf + counted vmcnt (grid 256 = 1 block/CU -> per-step drains were
// fully exposed; same pattern that helped qkv in R9). LDS 32 KB.
// ---------------------------------------------------------------------------
__global__ __launch_bounds__(256)
void out_mfma(const _Float16* __restrict__ ah,
              const _Float16* __restrict__ wth,
              const float* __restrict__ bias, float* __restrict__ out)
{
    __shared__ __align__(16) _Float16 SM[16384];    // 32 KB: [buf][A|B]

    const int tid  = threadIdx.x;
    const int lane = tid & 63;
    const int wave = tid >> 6;
    const int quad = lane >> 4;
    const int m    = lane & 15;
    const int wr   = wave >> 1, wc = wave & 1;

    // swizzle: XCD x owns row-blocks 8x..8x+7 (A slice 1MB + Wo-hi 0.5MB in L2)
    const int linear = blockIdx.x + (blockIdx.y << 6);   // 0..255
    const int xcd = linear & 7;
    const int r   = linear >> 3;                         // 0..31
    const int row0 = ((xcd << 3) + (r >> 2)) * 128;
    const int col0 = (r & 3) * 128;

    const size_t aoff0 = (size_t)(row0 + wave * 16 + m) * DM + (quad << 3);
    const size_t aoff1 = (size_t)(row0 + (wave + 4) * 16 + m) * DM + (quad << 3);
    const size_t boff0 = (size_t)(col0 + wave * 16 + m) * DM + (quad << 3);
    const size_t boff1 = (size_t)(col0 + (wave + 4) * 16 + m) * DM + (quad << 3);

    f32x4 acc[4][4];
#pragma unroll
    for (int i = 0; i < 4; ++i)
#pragma unroll
        for (int j = 0; j < 4; ++j) acc[i][j] = (f32x4){0.f, 0.f, 0.f, 0.f};

#define OSTAGE(b, kk) do {                                                    \
        async16(ah + aoff0 + (kk), &SM[((b) << 13) + (wave << 9)]);           \
        async16(ah + aoff1 + (kk), &SM[((b) << 13) + ((wave + 4) << 9)]);     \
        async16(wth + boff0 + (kk), &SM[((b) << 13) + 4096 + (wave << 9)]);   \
        async16(wth + boff1 + (kk), &SM[((b) << 13) + 4096 + ((wave + 4) << 9)]); \
    } while (0)

    OSTAGE(0, 0);
#pragma unroll 1
    for (int k0 = 0; k0 < DM; k0 += 32) {
        const int b = (k0 >> 5) & 1;
        if (k0 + 32 < DM) { OSTAGE(b ^ 1, k0 + 32); WAITVM(4); }
        else              { WAITVM(0); }
        BAR();

        const _Float16* Ah = &SM[b << 13];
        const _Float16* Bh = Ah + 4096;
        f16x8 av[4], bvh[4];
#pragma unroll
        for (int t = 0; t < 4; ++t) {
            int ai  = ((((wr << 2) + t) << 6) + lane) << 3;
            int bi2 = ((((wc << 2) + t) << 6) + lane) << 3;
            av[t]  = *(const f16x8*)&Ah[ai];
            bvh[t] = *(const f16x8*)&Bh[bi2];
        }
#pragma unroll
        for (int rt = 0; rt < 4; ++rt)
#pragma unroll
            for (int ct = 0; ct < 4; ++ct)
                acc[rt][ct] = MFMAH(av[rt], bvh[ct], acc[rt][ct]);
        LGKM0();
        BAR();
    }
#undef OSTAGE

    // epilogue: LDS transpose -> coalesced float4 stores
    const int row0w = row0 + wr * 64;
    const int colw  = col0 + wc * 64;
    float bc[4];
#pragma unroll
    for (int ct = 0; ct < 4; ++ct) bc[ct] = bias[colw + (ct << 4) + m];

    float* tb = (float*)SM + wave * 1088;
    const int rr = lane >> 2, jj = lane & 3;
#pragma unroll
    for (int rt = 0; rt < 4; ++rt) {
#pragma unroll
        for (int ct = 0; ct < 4; ++ct)
#pragma unroll
            for (int rg = 0; rg < 4; ++rg)
                tb[((quad << 2) + rg) * 68 + (ct << 4) + m] =
                    acc[rt][ct][rg] + bc[ct];
        LGKM0();
        int n = row0w + (rt << 4) + rr;
#pragma unroll
        for (int i = 0; i < 4; ++i) {
            int c = (jj << 2) + (i << 4);
            *(float4*)&out[(size_t)n * DM + colw + c] =
                *(const float4*)&tb[rr * 68 + c];
        }
    }
}

// ---------------------------------------------------------------------------
extern "C" void kernel_launch(void* const* d_in, const int* in_sizes, int n_in,
                              void* d_out, int out_size, void* d_ws, size_t ws_size,
                              hipStream_t stream)
{
    const float* x    = (const float*)d_in[0];
    const float* Wqkv = (const float*)d_in[1];
    const float* bqkv = (const float*)d_in[2];
    const float* Wo   = (const float*)d_in[3];
    const float* bo   = (const float*)d_in[4];
    float* out = (float*)d_out;

    char* ws = (char*)d_ws;
    const size_t MB = 1024 * 1024;
    _Float16* qh    = (_Float16*)(ws);                       // 8 MB [B,H,S,64]
    _Float16* oh    = (_Float16*)(ws + 8 * MB);              // 8 MB [B,S,512]
    _Float16* kh    = (_Float16*)(ws + 16 * MB);             // 8 MB [B,H,S,64]
    _Float16* vT    = (_Float16*)(ws + 24 * MB);             // 8 MB [B,H,64,S]
    _Float16* xh    = (_Float16*)(ws + 32 * MB);             // 8 MB [8192][512]
    _Float16* wqt_h = (_Float16*)(ws + 40 * MB);             // 1.5 MB [1536][512]
    _Float16* wot_h = (_Float16*)(ws + 42 * MB);             // 0.5 MB [512][512]
    float2*   rtab  = (float2*)(ws + 43 * MB);               // 0.5 MB [2048][32]

    prep_all<<<2560, 256, 0, stream>>>(x, Wqkv, Wo, rtab, wqt_h, wot_h, xh);
    qkv_mfma<<<dim3(64, 12), 256, 0, stream>>>(xh, wqt_h, bqkv, rtab,
                                               qh, kh, vT);
    attn_mfma<<<dim3(16, 32), 256, 0, stream>>>(qh, kh, vT, oh);
    out_mfma<<<dim3(64, 4), 256, 0, stream>>>(oh, wot_h, bo, out);
}